// Round 18
// baseline (1453.684 us; speedup 1.0000x reference)
//
#include <hip/hip_runtime.h>
#include <hip/hip_bf16.h>
#include <math.h>

// ---------------------------------------------------------------------------
// RAFT-small forward — round 18: r17 + zero-padded halo operand planes.
// The per-chunk `ok` border guard made every A-load conditional, blocking
// compiler load-hoisting across the static k-loop (VGPR=40, ~2 loads in
// flight). Now all hi/lo planes are [H+2][W+2][2][Cpad] with borders zeroed
// once (single hipMemsetAsync over the contiguous padded region); A-loads are
// unconditional (OOB taps read stored zeros == masked zeros, bit-identical).
// q's r*net chunks keep guards (fp32 bufs unpadded); corrS unpadded (1x1).
// ---------------------------------------------------------------------------

typedef __attribute__((ext_vector_type(8))) short short8;
typedef __attribute__((ext_vector_type(4))) float f32x4;

static inline int nblk(int n, int b){ return (n + b - 1) / b; }

__device__ __forceinline__ short bf16bits(float v){
  __hip_bfloat16 h = __float2bfloat16(v);
  return *reinterpret_cast<short*>(&h);
}
__device__ __forceinline__ float bf2f(short s){
  unsigned u = ((unsigned)(unsigned short)s) << 16;
  return *reinterpret_cast<float*>(&u);
}
__device__ __forceinline__ void split1(float v, unsigned short* hi, unsigned short* lo){
  short h = bf16bits(v);
  *hi = (unsigned short)h;
  *lo = (unsigned short)bf16bits(v - bf2f(h));
}
// bijective XCD swizzle (m204)
__device__ __forceinline__ int xcd_swz(int bid, int n){
  int q = n >> 3, r = n & 7;
  int x = bid & 7, k = bid >> 3;
  return (x < r ? x*(q+1) : r*(q+1) + (x-r)*q) + k;
}

// ---- init: netP fp32 (unpadded), netS/hxS padded interiors ----
__global__ void k_init_scale(const float* __restrict__ net_in, const float* __restrict__ inp_in,
                             float* __restrict__ netP, unsigned short* __restrict__ netS,
                             unsigned short* __restrict__ hxS,
                             float* __restrict__ coords, int H, int W)
{
  int HW = H*W;
  int i = blockIdx.x*256 + threadIdx.x;
  if (i >= HW*162) return;
  int p = i / 162, c = i - p*162;
  int PW = W + 2;
  size_t pq = (size_t)(p / W + 1)*PW + (p % W) + 1;
  if (c < 96){
    float t = tanhf(net_in[(size_t)c*HW + p]);
    netP[(size_t)p*96 + c] = t;
    split1(t, &netS[pq*192 + c], &netS[pq*192 + 96 + c]);
  } else if (c < 160){
    float r = fmaxf(inp_in[(size_t)(c-96)*HW + p], 0.f);
    split1(r, &hxS[pq*512 + c], &hxS[pq*512 + 256 + c]);
  } else if (c == 160){
    coords[p] = (float)(p % W);
  } else {
    coords[HW + p] = (float)(p / W);
  }
}
// f2 -> chunk-major [32][HW][4]; f1 -> [HW][128]
__global__ void k_transpose2(const float* __restrict__ f2, const float* __restrict__ f1,
                             float* __restrict__ f2c, float* __restrict__ f1h, int HW)
{
  int i = blockIdx.x*256 + threadIdx.x;
  int n = HW*128;
  if (i >= 2*n) return;
  if (i < n){
    int p = i >> 7, c = i & 127;
    f2c[((size_t)(c >> 2)*HW + p)*4 + (c & 3)] = f2[c*HW + p];
  } else {
    int k = i - n; int p = k >> 7, c = k & 127;
    f1h[k] = f1[c*HW + p];
  }
}
// 2x2 avg pool chunk-major
__global__ void k_pool_c4(const float* __restrict__ in, float* __restrict__ out, int H2, int W2){
  int i = blockIdx.x*256 + threadIdx.x;
  int HW2 = H2*W2;
  int n = 32*HW2*4;
  if (i >= n) return;
  int e = i & 3, rest = i >> 2;
  int p = rest % HW2, cc = rest / HW2;
  int ox = p % W2, oy = p / W2;
  int Win = 2*W2;
  size_t HWin = (size_t)(2*H2)*Win;
  const float* b = in + (cc*HWin + (size_t)(2*oy)*Win + 2*ox)*4 + e;
  out[i] = 0.25f*(b[0] + b[4] + b[(size_t)Win*4] + b[(size_t)Win*4 + 4]);
}
__global__ void k_cat2(const float* __restrict__ a, const float* __restrict__ b,
                       float* __restrict__ o, int n){
  int i = blockIdx.x*256 + threadIdx.x;
  if (i < 2*n) o[i] = (i < n) ? a[i] : b[i-n];
}

// ---- corr lookup + hx fill (corrS unpadded; hxS/netS padded) ----
__global__ __launch_bounds__(256)
void k_corr4(const float* __restrict__ f1h,
             const float* __restrict__ l0, const float* __restrict__ l1,
             const float* __restrict__ l2, const float* __restrict__ l3,
             const float* __restrict__ coords,
             unsigned short* __restrict__ corrS,
             unsigned short* __restrict__ hxS,
             const unsigned short* __restrict__ netS,
             int H, int W)
{
  int HW = H*W;
  int wv = threadIdx.x >> 6, lane = threadIdx.x & 63;
  int q = blockIdx.x*4 + wv;
  __shared__ __align__(16) float sf1[4][128];
  sf1[wv][lane]      = f1h[(size_t)q*128 + lane];
  sf1[wv][64 + lane] = f1h[(size_t)q*128 + 64 + lane];
  __syncthreads();
  float x = coords[q], y = coords[HW + q];
  const float* const lv[4] = {l0, l1, l2, l3};
  int u = lane & 7, v = lane >> 3;
  int t = lane;
  int j = min(t / 7, 6), k = min(t % 7, 6);
  const float4* a = (const float4*)&sf1[wv][0];
  #pragma unroll
  for (int i = 0; i < 4; i++){
    int Wi = W >> i, Hi = H >> i;
    size_t HWi = (size_t)Wi*Hi;
    float sc = 1.0f / (float)(1 << i);
    float xs = x*sc, ys = y*sc;
    float fx = floorf(xs), fy = floorf(ys);
    float wx = xs - fx, wy = ys - fy;
    float xf = fx + (float)(u - 3);
    float yf = fy + (float)(v - 3);
    float d = 0.0f;
    if (xf >= 0.0f && xf <= (float)(Wi-1) && yf >= 0.0f && yf <= (float)(Hi-1)){
      const float4* b = (const float4*)lv[i] + ((size_t)((int)yf)*Wi + (int)xf);
      float a0 = 0.f, a1 = 0.f, a2 = 0.f, a3 = 0.f;
      #pragma unroll
      for (int kk = 0; kk < 32; kk += 4){
        float4 av0 = a[kk],   bv0 = b[(size_t)kk*HWi];
        float4 av1 = a[kk+1], bv1 = b[(size_t)(kk+1)*HWi];
        float4 av2 = a[kk+2], bv2 = b[(size_t)(kk+2)*HWi];
        float4 av3 = a[kk+3], bv3 = b[(size_t)(kk+3)*HWi];
        a0 = fmaf(av0.x,bv0.x, fmaf(av0.y,bv0.y, fmaf(av0.z,bv0.z, fmaf(av0.w,bv0.w, a0))));
        a1 = fmaf(av1.x,bv1.x, fmaf(av1.y,bv1.y, fmaf(av1.z,bv1.z, fmaf(av1.w,bv1.w, a1))));
        a2 = fmaf(av2.x,bv2.x, fmaf(av2.y,bv2.y, fmaf(av2.z,bv2.z, fmaf(av2.w,bv2.w, a2))));
        a3 = fmaf(av3.x,bv3.x, fmaf(av3.y,bv3.y, fmaf(av3.z,bv3.z, fmaf(av3.w,bv3.w, a3))));
      }
      d = (a0 + a1) + (a2 + a3);
    }
    float d00 = __shfl(d,  k   *8 + j);
    float d10 = __shfl(d,  k   *8 + j + 1);
    float d01 = __shfl(d, (k+1)*8 + j);
    float d11 = __shfl(d, (k+1)*8 + j + 1);
    if (t < 49){
      float val = ((1.f-wx)*(1.f-wy)*d00 + wx*(1.f-wy)*d10
                + (1.f-wx)*wy*d01 + wx*wy*d11) * 0.08838834764831845f;
      split1(val, &corrS[(size_t)q*448 + i*49 + t], &corrS[(size_t)q*448 + 224 + i*49 + t]);
    }
  }
  if (lane < 28){
    corrS[(size_t)q*448 + 196 + lane] = 0;
    corrS[(size_t)q*448 + 224 + 196 + lane] = 0;
  }
  int PW = W + 2;
  size_t pq = (size_t)(q / W + 1)*PW + (q % W) + 1;
  hxS[pq*512 + lane]       = netS[pq*192 + lane];
  hxS[pq*512 + 256 + lane] = netS[pq*192 + 96 + lane];
  if (lane < 32){
    hxS[pq*512 + 64 + lane]       = netS[pq*192 + 64 + lane];
    hxS[pq*512 + 256 + 64 + lane] = netS[pq*192 + 96 + 64 + lane];
  } else if (lane == 32){
    split1(x - (float)(q % W), &hxS[pq*512 + 240], &hxS[pq*512 + 256 + 240]);
  } else if (lane == 33){
    split1(y - (float)(q / W), &hxS[pq*512 + 241], &hxS[pq*512 + 256 + 241]);
  }
}

// ---- combined upsampler (unchanged) ----
__global__ void k_upflow2(const float* __restrict__ cin, float* __restrict__ pred,
                          int Hin, int Win, float s,
                          float* __restrict__ conext, int Hf)
{
  int idx = blockIdx.x*256 + threadIdx.x;
  const int HWp = 192*192;
  int c, py, px, Hout, Wout;
  float n; int subtract; float* outp; size_t oidx;
  if (idx < 2*HWp){
    c = idx / HWp; int rem = idx - c*HWp; py = rem / 192; px = rem % 192;
    Hout = 192; Wout = 192; n = s; subtract = 1; outp = pred; oidx = idx;
  } else {
    int k2 = idx - 2*HWp;
    int HWf = Hf*Hf;
    if (Hf == 0 || k2 >= 2*HWf) return;
    c = k2 / HWf; int rem = k2 - c*HWf; py = rem / Hf; px = rem % Hf;
    Hout = Hf; Wout = Hf; n = 2.f; subtract = 0; outp = conext; oidx = k2;
  }
  float posy = (float)py * (float)(Hin-1) / (float)(Hout-1);
  float posx = (float)px * (float)(Win-1) / (float)(Wout-1);
  int iy = (int)floorf(posy); iy = max(0, min(iy, Hin-2));
  int ix = (int)floorf(posx); ix = max(0, min(ix, Win-2));
  float wy = posy - (float)iy, wx = posx - (float)ix;
  const float* base = cin + (size_t)c*Hin*Win;
  float s00 = 0.f, s10 = 0.f, s01 = 0.f, s11 = 0.f;
  if (subtract){
    if (c == 0){ s00 = (float)ix; s01 = (float)ix; s10 = (float)(ix+1); s11 = (float)(ix+1); }
    else       { s00 = (float)iy; s10 = (float)iy; s01 = (float)(iy+1); s11 = (float)(iy+1); }
  }
  float v00 = base[(size_t)iy*Win + ix]       - s00;
  float v10 = base[(size_t)iy*Win + ix + 1]   - s10;
  float v01 = base[(size_t)(iy+1)*Win + ix]   - s01;
  float v11 = base[(size_t)(iy+1)*Win + ix+1] - s11;
  float val = (1.f-wy)*((1.f-wx)*v00 + wx*v10) + wy*((1.f-wx)*v01 + wx*v11);
  outp[oidx] = n * val;
}

// ---- pack-B (unchanged) ----
__global__ void k_packb(const float* __restrict__ w0, const float* __restrict__ w1,
                        int split, int Cout, int Cin, int KT, int CH32, int mode,
                        short8* __restrict__ out, int nt16, int KTN)
{
  int gid = blockIdx.x*256 + threadIdx.x;
  if (gid >= KTN*nt16*64) return;
  int lane = gid & 63, blk = gid >> 6;
  int ct = blk % nt16, kt = blk / nt16;
  int col = ct*16 + (lane & 15);
  int tap = kt / CH32, chunk = kt - tap*CH32;
  int ci0 = chunk*32 + (lane >> 4)*8;
  short8 hi8, lo8;
  #pragma unroll
  for (int e = 0; e < 8; e++){
    int ci = ci0 + e;
    float v = 0.f;
    if (col < Cout && ci < Cin && tap < KT){
      if (mode == 1){
        v = w0[((size_t)col*2 + (ci & 1))*49 + (ci >> 1)];
      } else {
        const float* wp = (col < split) ? (w0 + (size_t)col*Cin*KT)
                                        : (w1 + (size_t)(col - split)*Cin*KT);
        v = wp[(size_t)ci*KT + tap];
      }
    }
    short h = bf16bits(v);
    hi8[e] = h;
    lo8[e] = bf16bits(v - bf2f(h));
  }
  out[(size_t)blk*128 + lane]      = hi8;
  out[(size_t)blk*128 + 64 + lane] = lo8;
}

// ---------------------------------------------------------------------------
// GEMM: static k-loop + XCD swizzle; PAD=1 -> unconditional A loads from
// halo-padded planes; outS writes always padded. NQ chunks keep guards.
// ---------------------------------------------------------------------------
template<int KTW, int CH32, int FM, int ACT, int EPI, int NQ, int NF, int PAD>
__global__ __launch_bounds__(256)
void k_fgemm(const unsigned short* __restrict__ A, int Cpad,
             const float* __restrict__ zr_, const float* __restrict__ net_,
             const float* __restrict__ coF,
             const short8* __restrict__ B, int nt16, const float* __restrict__ bias,
             float* __restrict__ outF, int osF, int ooF,
             unsigned short* __restrict__ outS, int CpadS, int ooS,
             int Cout, int H, int W,
             const float* __restrict__ ez, int ezs,
             const float* __restrict__ eold, int eos)
{
  constexpr int KT = KTW*KTW, P = KTW/2;
  int HW = H*W;
  int PW = W + 2;
  int lane = threadIdx.x & 63;
  int nb = gridDim.x*gridDim.y;
  int wg = xcd_swz(blockIdx.y*gridDim.x + blockIdx.x, nb);
  int by = wg % gridDim.y;
  int bx = wg / gridDim.y;
  int mt = bx*4 + (threadIdx.x >> 6);
  int ct0 = by*NF;
  int p = mt*16 + (lane & 15);
  int x = p % W, y = p / W;
  int kq = (lane >> 4)*8;

  f32x4 acc[NF];
  #pragma unroll
  for (int f = 0; f < NF; f++) acc[f] = f32x4{0.f,0.f,0.f,0.f};
  const short8 zero8 = short8{0,0,0,0,0,0,0,0};

  #pragma unroll
  for (int tap = 0; tap < KT; tap++){
    const int dx = tap % KTW - P, dy = tap / KTW - P;
    int xx = x + dx, yy = y + dy;
    const unsigned short* arow;
    bool ok;
    if (PAD){
      arow = A + (size_t)((yy+1)*PW + xx + 1)*2*Cpad;
      ok = true;
    } else {
      ok = ((unsigned)xx < (unsigned)W) && ((unsigned)yy < (unsigned)H);
      arow = A + (size_t)(yy*W + xx)*2*Cpad;
    }
    int baseu = yy*W + xx;   // unpadded base for NQ fp32 reads
    bool okq = ((unsigned)xx < (unsigned)W) && ((unsigned)yy < (unsigned)H);
    #pragma unroll
    for (int c = 0; c < CH32; c++){
      int kt = tap*CH32 + c;
      short8 ah = zero8, al = zero8;
      if constexpr (FM == 2){
        float vv[8];
        #pragma unroll
        for (int e = 0; e < 8; e++){
          int ci = c*32 + kq + e;
          float v = 0.f;
          if (ci < 98){
            int t7 = ci >> 1, jj = ci & 1;
            int ddx = t7 % 7 - 3, ddy = t7 / 7 - 3;
            int x2 = x + ddx, y2 = y + ddy;
            if ((unsigned)x2 < (unsigned)W && (unsigned)y2 < (unsigned)H)
              v = coF[(size_t)jj*HW + y2*W + x2] - (float)(jj ? y2 : x2);
          }
          vv[e] = v;
        }
        #pragma unroll
        for (int e = 0; e < 8; e++){
          short h = bf16bits(vv[e]);
          ah[e] = h;
          al[e] = bf16bits(vv[e] - bf2f(h));
        }
      } else if (NQ > 0 && c < NQ){
        if (okq){
          const float4* zp = (const float4*)(zr_ + (size_t)baseu*192 + 96 + c*32 + kq);
          const float4* np = (const float4*)(net_ + (size_t)baseu*96 + c*32 + kq);
          float4 z0 = zp[0], z1 = zp[1], n0 = np[0], n1 = np[1];
          float vv[8] = {z0.x*n0.x, z0.y*n0.y, z0.z*n0.z, z0.w*n0.w,
                         z1.x*n1.x, z1.y*n1.y, z1.z*n1.z, z1.w*n1.w};
          #pragma unroll
          for (int e = 0; e < 8; e++){
            short h = bf16bits(vv[e]);
            ah[e] = h;
            al[e] = bf16bits(vv[e] - bf2f(h));
          }
        }
      } else {
        if (PAD || ok){
          const unsigned short* ap = arow + c*32 + kq;
          ah = *(const short8*)ap;
          al = *(const short8*)(ap + Cpad);
        }
      }
      const short8* bp = B + ((size_t)kt*nt16 + ct0)*128 + lane;
      #pragma unroll
      for (int f = 0; f < NF; f++){
        short8 bh = bp[(size_t)f*128], bl = bp[(size_t)f*128 + 64];
        acc[f] = __builtin_amdgcn_mfma_f32_16x16x32_bf16(ah, bh, acc[f], 0, 0, 0);
        acc[f] = __builtin_amdgcn_mfma_f32_16x16x32_bf16(al, bh, acc[f], 0, 0, 0);
        acc[f] = __builtin_amdgcn_mfma_f32_16x16x32_bf16(ah, bl, acc[f], 0, 0, 0);
      }
    }
  }

  int rowb = mt*16 + ((lane >> 4) << 2);
  int colq = lane & 15;
  #pragma unroll
  for (int f = 0; f < NF; f++){
    int col = (ct0 + f)*16 + colq;
    if (col < Cout){
      float bb = bias[col];
      #pragma unroll
      for (int r = 0; r < 4; r++){
        float val = acc[f][r] + bb;
        if (ACT == 1) val = fmaxf(val, 0.f);
        if (ACT == 2) val = 1.f/(1.f + expf(-val));
        if (ACT == 3) val = tanhf(val);
        int row = rowb + r;
        if constexpr (EPI == 2){
          outF[(size_t)col*HW + row] += val;
        } else {
          if constexpr (EPI == 1){
            float zz = ez[(size_t)row*ezs + col];
            val = (1.f - zz)*eold[(size_t)row*eos + col] + zz*val;
          }
          if constexpr (EPI == 1 || EPI == 3)
            outF[(size_t)row*osF + ooF + col] = val;
          if constexpr (EPI == 0 || EPI == 1){
            int pyo = row / W, pxo = row - pyo*W;
            size_t op = (size_t)((pyo+1)*PW + pxo + 1);
            split1(val, &outS[op*2*CpadS + ooS + col],
                        &outS[op*2*CpadS + CpadS + ooS + col]);
          }
        }
      }
    }
  }
}

extern "C" void kernel_launch(void* const* d_in, const int* in_sizes, int n_in,
                              void* d_out, int out_size, void* d_ws, size_t ws_size,
                              hipStream_t stream)
{
  (void)in_sizes; (void)n_in; (void)out_size; (void)ws_size;
  const float* f1s[3]    = {(const float*)d_in[0], (const float*)d_in[2], (const float*)d_in[4]};
  const float* f2s[3]    = {(const float*)d_in[1], (const float*)d_in[3], (const float*)d_in[5]};
  const float* net_in[3] = {(const float*)d_in[6], (const float*)d_in[8], (const float*)d_in[10]};
  const float* inp_in[3] = {(const float*)d_in[7], (const float*)d_in[9], (const float*)d_in[11]};
  const float* Wc1 = (const float*)d_in[12]; const float* bc1 = (const float*)d_in[13];
  const float* Wf1 = (const float*)d_in[14]; const float* bf1 = (const float*)d_in[15];
  const float* Wf2 = (const float*)d_in[16]; const float* bf2 = (const float*)d_in[17];
  const float* Wm  = (const float*)d_in[18]; const float* bm  = (const float*)d_in[19];
  const float* Wz  = (const float*)d_in[20]; const float* bz  = (const float*)d_in[21];
  const float* Wr  = (const float*)d_in[22]; const float* br  = (const float*)d_in[23];
  const float* Wq  = (const float*)d_in[24]; const float* bq  = (const float*)d_in[25];
  const float* Wh1 = (const float*)d_in[26]; const float* bh1 = (const float*)d_in[27];
  const float* Wh2 = (const float*)d_in[28]; const float* bh2 = (const float*)d_in[29];

  const int Hs[3] = {96, 48, 24};

  float* ws = (float*)d_ws;
  size_t off = 0;
  auto alloc = [&](size_t nfl)->float*{
    float* p = ws + off;
    off += (nfl + 3) & ~((size_t)3);
    return p;
  };

  // unpadded buffers
  float* f2l[3][4]; float* f1h[3]; float* netP[3][2]; float* coords[3];
  for (int si = 0; si < 3; si++){
    int H = Hs[si], HW = H*H;
    for (int l = 0; l < 4; l++) f2l[si][l] = alloc((size_t)(HW >> (2*l))*128);
    f1h[si]     = alloc((size_t)HW*128);
    netP[si][0] = alloc((size_t)HW*96);
    netP[si][1] = alloc((size_t)HW*96);
    coords[si]  = alloc((size_t)2*HW);
  }
  const int HWm = 96*96;
  unsigned short* corrS = (unsigned short*)alloc((size_t)HWm*224);
  float* zrb = alloc((size_t)HWm*192);
  float* Bc1 = alloc((size_t)7*6*512);
  float* Bf1 = alloc((size_t)4*4*512);
  float* Bf2 = alloc((size_t)18*2*512);
  float* Bm  = alloc((size_t)36*6*512);
  float* Bzr = alloc((size_t)72*12*512);
  float* Bq  = alloc((size_t)72*6*512);
  float* Bh1 = alloc((size_t)27*8*512);
  float* Bh2 = alloc((size_t)36*1*512);
  float* bzr = alloc(192);

  // padded hi/lo planes (contiguous region, memset once per call)
  float* padBase = ws + off;
  unsigned short* netS[3][2]; unsigned short* hxS[3];
  unsigned short* flo1S[3]; unsigned short* cminS[3]; unsigned short* t128S[3];
  for (int si = 0; si < 3; si++){
    int PH = Hs[si] + 2;
    size_t PP = (size_t)PH*PH;
    netS[si][0] = (unsigned short*)alloc(PP*96);
    netS[si][1] = (unsigned short*)alloc(PP*96);
    hxS[si]     = (unsigned short*)alloc(PP*256);
    flo1S[si]   = (unsigned short*)alloc(PP*64);
    cminS[si]   = (unsigned short*)alloc(PP*128);
    t128S[si]   = (unsigned short*)alloc(PP*128);
  }
  size_t padBytes = (size_t)((ws + off) - padBase) * 4;
  hipMemsetAsync(padBase, 0, padBytes, stream);

  #define NB(n) dim3((unsigned)nblk((n), 256))

  // ---- one-time B packs ----
  k_packb<<<NB(7*6*64),  256,0,stream>>>(Wc1, Wc1, 96, 96, 196, 1, 7, 0, (short8*)Bc1, 6, 7);
  k_packb<<<NB(4*4*64),  256,0,stream>>>(Wf1, Wf1, 64, 64,  98, 1, 4, 1, (short8*)Bf1, 4, 4);
  k_packb<<<NB(18*2*64), 256,0,stream>>>(Wf2, Wf2, 32, 32,  64, 9, 2, 0, (short8*)Bf2, 2, 18);
  k_packb<<<NB(36*6*64), 256,0,stream>>>(Wm,  Wm,  80, 80, 128, 9, 4, 0, (short8*)Bm,  6, 36);
  k_packb<<<NB(72*12*64),256,0,stream>>>(Wz,  Wr,  96, 192,242, 9, 8, 0, (short8*)Bzr, 12, 72);
  k_packb<<<NB(72*6*64), 256,0,stream>>>(Wq,  Wq,  96, 96, 242, 9, 8, 0, (short8*)Bq,  6, 72);
  k_packb<<<NB(27*8*64), 256,0,stream>>>(Wh1, Wh1,128, 128, 96, 9, 3, 0, (short8*)Bh1, 8, 27);
  k_packb<<<NB(36*1*64), 256,0,stream>>>(Wh2, Wh2,  2,   2,128, 9, 4, 0, (short8*)Bh2, 1, 36);
  k_cat2<<<dim3(1), 256, 0, stream>>>(bz, br, bzr, 96);

  // ---- per-scale init ----
  for (int si = 0; si < 3; si++){
    int H = Hs[si], HW = H*H;
    k_init_scale<<<NB(HW*162), 256,0,stream>>>(net_in[si], inp_in[si], netP[si][0],
                                               netS[si][0], hxS[si], coords[si], H, H);
    k_transpose2<<<NB(2*HW*128), 256,0,stream>>>(f2s[si], f1s[si], f2l[si][0], f1h[si], HW);
    for (int l = 1; l < 4; l++){
      int Hl = H >> l;
      k_pool_c4<<<NB(32*Hl*Hl*4), 256,0,stream>>>(f2l[si][l-1], f2l[si][l], Hl, Hl);
    }
  }

  int cur[3] = {0, 0, 0};
  const int seq[6] = {2, 2, 1, 1, 0, 0};
  for (int it = 0; it < 6; it++){
    int si = seq[it];
    int H = Hs[si], W = H, HW = H*W;
    int MT = HW/16;
    float s = (si == 0) ? 2.0f : ((si == 1) ? 4.0f : 8.0f);
    float* netcF = netP[si][cur[si]];
    float* netnF = netP[si][cur[si]^1];
    unsigned short* netcS = netS[si][cur[si]];
    unsigned short* netnS = netS[si][cur[si]^1];
    float* co = coords[si];
    unsigned short* hx = hxS[si];
    unsigned gx = (unsigned)(MT/4);
    bool big = (si == 0);

    k_corr4<<<dim3((unsigned)(HW/4)), 256,0,stream>>>(
        f1h[si], f2l[si][0], f2l[si][1], f2l[si][2], f2l[si][3], co,
        corrS, hx, netcS, H, W);

    // c1 (1x1, corrS unpadded -> cminS, relu)
    if (big) k_fgemm<1,7,0,1,0,0,3,0><<<dim3(gx,2), 256,0,stream>>>(corrS,224, nullptr,nullptr,nullptr,
        (short8*)Bc1, 6, bc1, nullptr,0,0, cminS[si],128,0, 96, H,W, nullptr,0, nullptr,0);
    else     k_fgemm<1,7,0,1,0,0,2,0><<<dim3(gx,3), 256,0,stream>>>(corrS,224, nullptr,nullptr,nullptr,
        (short8*)Bc1, 6, bc1, nullptr,0,0, cminS[si],128,0, 96, H,W, nullptr,0, nullptr,0);
    // f1 (7x7 flow-im2row -> flo1S, relu)
    k_fgemm<1,4,2,1,0,0,2,0><<<dim3(gx,2), 256,0,stream>>>(nullptr,0, nullptr,nullptr,co,
        (short8*)Bf1, 4, bf1, nullptr,0,0, flo1S[si],64,0, 64, H,W, nullptr,0, nullptr,0);
    // f2 (3x3, flo1S padded -> cminS[96..127], relu)
    k_fgemm<3,2,0,1,0,0,2,1><<<dim3(gx,1), 256,0,stream>>>(flo1S[si],64, nullptr,nullptr,nullptr,
        (short8*)Bf2, 2, bf2, nullptr,0,0, cminS[si],128,96, 32, H,W, nullptr,0, nullptr,0);
    // m (3x3, cminS padded -> hxS[160..239], relu)
    if (big) k_fgemm<3,4,0,1,0,0,3,1><<<dim3(gx,2), 256,0,stream>>>(cminS[si],128, nullptr,nullptr,nullptr,
        (short8*)Bm, 6, bm, nullptr,0,0, hx,256,160, 80, H,W, nullptr,0, nullptr,0);
    else     k_fgemm<3,4,0,1,0,0,2,1><<<dim3(gx,3), 256,0,stream>>>(cminS[si],128, nullptr,nullptr,nullptr,
        (short8*)Bm, 6, bm, nullptr,0,0, hx,256,160, 80, H,W, nullptr,0, nullptr,0);
    // zr (3x3, hxS padded -> zrb fp32, sigmoid)
    if (big) k_fgemm<3,8,0,2,3,0,4,1><<<dim3(gx,3), 256,0,stream>>>(hx,256, nullptr,nullptr,nullptr,
        (short8*)Bzr, 12, bzr, zrb,192,0, nullptr,0,0, 192, H,W, nullptr,0, nullptr,0);
    else     k_fgemm<3,8,0,2,3,0,2,1><<<dim3(gx,6), 256,0,stream>>>(hx,256, nullptr,nullptr,nullptr,
        (short8*)Bzr, 12, bzr, zrb,192,0, nullptr,0,0, 192, H,W, nullptr,0, nullptr,0);
    // q (3x3, [r*net guarded | hxS padded] -> GRU -> netn fp32 + padded hi/lo)
    if (big) k_fgemm<3,8,0,3,1,3,3,1><<<dim3(gx,2), 256,0,stream>>>(hx,256, zrb,netcF,nullptr,
        (short8*)Bq, 6, bq, netnF,96,0, netnS,96,0, 96, H,W, zrb,192, netcF,96);
    else     k_fgemm<3,8,0,3,1,3,2,1><<<dim3(gx,3), 256,0,stream>>>(hx,256, zrb,netcF,nullptr,
        (short8*)Bq, 6, bq, netnF,96,0, netnS,96,0, 96, H,W, zrb,192, netcF,96);
    // fh1 (3x3, netnS padded -> t128S, relu)
    if (big) k_fgemm<3,3,0,1,0,0,4,1><<<dim3(gx,2), 256,0,stream>>>(netnS,96, nullptr,nullptr,nullptr,
        (short8*)Bh1, 8, bh1, nullptr,0,0, t128S[si],128,0, 128, H,W, nullptr,0, nullptr,0);
    else     k_fgemm<3,3,0,1,0,0,2,1><<<dim3(gx,4), 256,0,stream>>>(netnS,96, nullptr,nullptr,nullptr,
        (short8*)Bh1, 8, bh1, nullptr,0,0, t128S[si],128,0, 128, H,W, nullptr,0, nullptr,0);
    // fh2 (3x3, t128S padded -> coords CHW +=)
    k_fgemm<3,4,0,0,2,0,1,1><<<dim3(gx,1), 256,0,stream>>>(t128S[si],128, nullptr,nullptr,nullptr,
        (short8*)Bh2, 1, bh2, co,0,0, nullptr,0,0, 2, H,W, nullptr,0, nullptr,0);

    int Hf = (si > 0) ? Hs[si-1] : 0;
    float* conext = (si > 0) ? coords[si-1] : nullptr;
    k_upflow2<<<NB(2*192*192 + (Hf ? 2*Hf*Hf : 0)), 256,0,stream>>>(
        co, (float*)d_out + (size_t)it*2*192*192, H, W, s, conext, Hf);

    cur[si] ^= 1;
  }
  #undef NB
}

// Round 19
// 1283.263 us; speedup vs baseline: 1.1328x; 1.1328x over previous
//
#include <hip/hip_runtime.h>
#include <hip/hip_bf16.h>
#include <math.h>

// ---------------------------------------------------------------------------
// RAFT-small forward — round 19: r17 base (best, 1303us) + split-K=2 on the
// three heavy 96² GEMMs (zr, q, fh1). r18 padding reverted (epilogue div +
// memset + border-fetch regressions). Split-K adds resident waves WITHOUT
// changing per-wave A/B traffic (r16 showed column-pass duplication hurts):
// blockIdx.z picks tap half; raw fp32 partials; k_red does bias+act(+GRU)
// + hi/lo split. Everything else identical to r17.
// ---------------------------------------------------------------------------

typedef __attribute__((ext_vector_type(8))) short short8;
typedef __attribute__((ext_vector_type(4))) float f32x4;

static inline int nblk(int n, int b){ return (n + b - 1) / b; }

__device__ __forceinline__ short bf16bits(float v){
  __hip_bfloat16 h = __float2bfloat16(v);
  return *reinterpret_cast<short*>(&h);
}
__device__ __forceinline__ float bf2f(short s){
  unsigned u = ((unsigned)(unsigned short)s) << 16;
  return *reinterpret_cast<float*>(&u);
}
__device__ __forceinline__ void split1(float v, unsigned short* hi, unsigned short* lo){
  short h = bf16bits(v);
  *hi = (unsigned short)h;
  *lo = (unsigned short)bf16bits(v - bf2f(h));
}
// bijective XCD swizzle (m204)
__device__ __forceinline__ int xcd_swz(int bid, int n){
  int q = n >> 3, r = n & 7;
  int x = bid & 7, k = bid >> 3;
  return (x < r ? x*(q+1) : r*(q+1) + (x-r)*q) + k;
}

// ---- init ----
__global__ void k_init_scale(const float* __restrict__ net_in, const float* __restrict__ inp_in,
                             float* __restrict__ netP, unsigned short* __restrict__ netS,
                             unsigned short* __restrict__ hxS,
                             float* __restrict__ coords, int H, int W)
{
  int HW = H*W;
  int i = blockIdx.x*256 + threadIdx.x;
  if (i >= HW*176) return;
  int p = i / 176, c = i - p*176;
  if (c < 96){
    float t = tanhf(net_in[(size_t)c*HW + p]);
    netP[(size_t)p*96 + c] = t;
    split1(t, &netS[(size_t)p*192 + c], &netS[(size_t)p*192 + 96 + c]);
  } else if (c < 160){
    float r = fmaxf(inp_in[(size_t)(c-96)*HW + p], 0.f);
    split1(r, &hxS[(size_t)p*512 + c], &hxS[(size_t)p*512 + 256 + c]);
  } else if (c < 174){
    int col = 242 + (c - 160);
    hxS[(size_t)p*512 + col] = 0;
    hxS[(size_t)p*512 + 256 + col] = 0;
  } else if (c == 174){
    coords[p] = (float)(p % W);
  } else {
    coords[HW + p] = (float)(p / W);
  }
}
// f2 -> chunk-major [32][HW][4]; f1 -> [HW][128]
__global__ void k_transpose2(const float* __restrict__ f2, const float* __restrict__ f1,
                             float* __restrict__ f2c, float* __restrict__ f1h, int HW)
{
  int i = blockIdx.x*256 + threadIdx.x;
  int n = HW*128;
  if (i >= 2*n) return;
  if (i < n){
    int p = i >> 7, c = i & 127;
    f2c[((size_t)(c >> 2)*HW + p)*4 + (c & 3)] = f2[c*HW + p];
  } else {
    int k = i - n; int p = k >> 7, c = k & 127;
    f1h[k] = f1[c*HW + p];
  }
}
// 2x2 avg pool chunk-major
__global__ void k_pool_c4(const float* __restrict__ in, float* __restrict__ out, int H2, int W2){
  int i = blockIdx.x*256 + threadIdx.x;
  int HW2 = H2*W2;
  int n = 32*HW2*4;
  if (i >= n) return;
  int e = i & 3, rest = i >> 2;
  int p = rest % HW2, cc = rest / HW2;
  int ox = p % W2, oy = p / W2;
  int Win = 2*W2;
  size_t HWin = (size_t)(2*H2)*Win;
  const float* b = in + (cc*HWin + (size_t)(2*oy)*Win + 2*ox)*4 + e;
  out[i] = 0.25f*(b[0] + b[4] + b[(size_t)Win*4] + b[(size_t)Win*4 + 4]);
}
__global__ void k_cat2(const float* __restrict__ a, const float* __restrict__ b,
                       float* __restrict__ o, int n){
  int i = blockIdx.x*256 + threadIdx.x;
  if (i < 2*n) o[i] = (i < n) ? a[i] : b[i-n];
}

// ---- corr lookup + hx fill (r17, unchanged) ----
__global__ __launch_bounds__(256)
void k_corr4(const float* __restrict__ f1h,
             const float* __restrict__ l0, const float* __restrict__ l1,
             const float* __restrict__ l2, const float* __restrict__ l3,
             const float* __restrict__ coords,
             unsigned short* __restrict__ corrS,
             unsigned short* __restrict__ hxS,
             const unsigned short* __restrict__ netS,
             int H, int W)
{
  int HW = H*W;
  int wv = threadIdx.x >> 6, lane = threadIdx.x & 63;
  int q = blockIdx.x*4 + wv;
  __shared__ __align__(16) float sf1[4][128];
  sf1[wv][lane]      = f1h[(size_t)q*128 + lane];
  sf1[wv][64 + lane] = f1h[(size_t)q*128 + 64 + lane];
  __syncthreads();
  float x = coords[q], y = coords[HW + q];
  const float* const lv[4] = {l0, l1, l2, l3};
  int u = lane & 7, v = lane >> 3;
  int t = lane;
  int j = min(t / 7, 6), k = min(t % 7, 6);
  const float4* a = (const float4*)&sf1[wv][0];
  #pragma unroll
  for (int i = 0; i < 4; i++){
    int Wi = W >> i, Hi = H >> i;
    size_t HWi = (size_t)Wi*Hi;
    float sc = 1.0f / (float)(1 << i);
    float xs = x*sc, ys = y*sc;
    float fx = floorf(xs), fy = floorf(ys);
    float wx = xs - fx, wy = ys - fy;
    float xf = fx + (float)(u - 3);
    float yf = fy + (float)(v - 3);
    float d = 0.0f;
    if (xf >= 0.0f && xf <= (float)(Wi-1) && yf >= 0.0f && yf <= (float)(Hi-1)){
      const float4* b = (const float4*)lv[i] + ((size_t)((int)yf)*Wi + (int)xf);
      float a0 = 0.f, a1 = 0.f, a2 = 0.f, a3 = 0.f;
      #pragma unroll
      for (int kk = 0; kk < 32; kk += 4){
        float4 av0 = a[kk],   bv0 = b[(size_t)kk*HWi];
        float4 av1 = a[kk+1], bv1 = b[(size_t)(kk+1)*HWi];
        float4 av2 = a[kk+2], bv2 = b[(size_t)(kk+2)*HWi];
        float4 av3 = a[kk+3], bv3 = b[(size_t)(kk+3)*HWi];
        a0 = fmaf(av0.x,bv0.x, fmaf(av0.y,bv0.y, fmaf(av0.z,bv0.z, fmaf(av0.w,bv0.w, a0))));
        a1 = fmaf(av1.x,bv1.x, fmaf(av1.y,bv1.y, fmaf(av1.z,bv1.z, fmaf(av1.w,bv1.w, a1))));
        a2 = fmaf(av2.x,bv2.x, fmaf(av2.y,bv2.y, fmaf(av2.z,bv2.z, fmaf(av2.w,bv2.w, a2))));
        a3 = fmaf(av3.x,bv3.x, fmaf(av3.y,bv3.y, fmaf(av3.z,bv3.z, fmaf(av3.w,bv3.w, a3))));
      }
      d = (a0 + a1) + (a2 + a3);
    }
    float d00 = __shfl(d,  k   *8 + j);
    float d10 = __shfl(d,  k   *8 + j + 1);
    float d01 = __shfl(d, (k+1)*8 + j);
    float d11 = __shfl(d, (k+1)*8 + j + 1);
    if (t < 49){
      float val = ((1.f-wx)*(1.f-wy)*d00 + wx*(1.f-wy)*d10
                + (1.f-wx)*wy*d01 + wx*wy*d11) * 0.08838834764831845f;
      split1(val, &corrS[(size_t)q*448 + i*49 + t], &corrS[(size_t)q*448 + 224 + i*49 + t]);
    }
  }
  if (lane < 28){
    corrS[(size_t)q*448 + 196 + lane] = 0;
    corrS[(size_t)q*448 + 224 + 196 + lane] = 0;
  }
  hxS[(size_t)q*512 + lane]       = netS[(size_t)q*192 + lane];
  hxS[(size_t)q*512 + 256 + lane] = netS[(size_t)q*192 + 96 + lane];
  if (lane < 32){
    hxS[(size_t)q*512 + 64 + lane]       = netS[(size_t)q*192 + 64 + lane];
    hxS[(size_t)q*512 + 256 + 64 + lane] = netS[(size_t)q*192 + 96 + 64 + lane];
  } else if (lane == 32){
    split1(x - (float)(q % W), &hxS[(size_t)q*512 + 240], &hxS[(size_t)q*512 + 256 + 240]);
  } else if (lane == 33){
    split1(y - (float)(q / W), &hxS[(size_t)q*512 + 241], &hxS[(size_t)q*512 + 256 + 241]);
  }
}

// ---- combined upsampler (unchanged) ----
__global__ void k_upflow2(const float* __restrict__ cin, float* __restrict__ pred,
                          int Hin, int Win, float s,
                          float* __restrict__ conext, int Hf)
{
  int idx = blockIdx.x*256 + threadIdx.x;
  const int HWp = 192*192;
  int c, py, px, Hout, Wout;
  float n; int subtract; float* outp; size_t oidx;
  if (idx < 2*HWp){
    c = idx / HWp; int rem = idx - c*HWp; py = rem / 192; px = rem % 192;
    Hout = 192; Wout = 192; n = s; subtract = 1; outp = pred; oidx = idx;
  } else {
    int k2 = idx - 2*HWp;
    int HWf = Hf*Hf;
    if (Hf == 0 || k2 >= 2*HWf) return;
    c = k2 / HWf; int rem = k2 - c*HWf; py = rem / Hf; px = rem % Hf;
    Hout = Hf; Wout = Hf; n = 2.f; subtract = 0; outp = conext; oidx = k2;
  }
  float posy = (float)py * (float)(Hin-1) / (float)(Hout-1);
  float posx = (float)px * (float)(Win-1) / (float)(Wout-1);
  int iy = (int)floorf(posy); iy = max(0, min(iy, Hin-2));
  int ix = (int)floorf(posx); ix = max(0, min(ix, Win-2));
  float wy = posy - (float)iy, wx = posx - (float)ix;
  const float* base = cin + (size_t)c*Hin*Win;
  float s00 = 0.f, s10 = 0.f, s01 = 0.f, s11 = 0.f;
  if (subtract){
    if (c == 0){ s00 = (float)ix; s01 = (float)ix; s10 = (float)(ix+1); s11 = (float)(ix+1); }
    else       { s00 = (float)iy; s10 = (float)iy; s01 = (float)(iy+1); s11 = (float)(iy+1); }
  }
  float v00 = base[(size_t)iy*Win + ix]       - s00;
  float v10 = base[(size_t)iy*Win + ix + 1]   - s10;
  float v01 = base[(size_t)(iy+1)*Win + ix]   - s01;
  float v11 = base[(size_t)(iy+1)*Win + ix+1] - s11;
  float val = (1.f-wy)*((1.f-wx)*v00 + wx*v10) + wy*((1.f-wx)*v01 + wx*v11);
  outp[oidx] = n * val;
}

// ---- pack-B (unchanged) ----
__global__ void k_packb(const float* __restrict__ w0, const float* __restrict__ w1,
                        int split, int Cout, int Cin, int KT, int CH32, int mode,
                        short8* __restrict__ out, int nt16, int KTN)
{
  int gid = blockIdx.x*256 + threadIdx.x;
  if (gid >= KTN*nt16*64) return;
  int lane = gid & 63, blk = gid >> 6;
  int ct = blk % nt16, kt = blk / nt16;
  int col = ct*16 + (lane & 15);
  int tap = kt / CH32, chunk = kt - tap*CH32;
  int ci0 = chunk*32 + (lane >> 4)*8;
  short8 hi8, lo8;
  #pragma unroll
  for (int e = 0; e < 8; e++){
    int ci = ci0 + e;
    float v = 0.f;
    if (col < Cout && ci < Cin && tap < KT){
      if (mode == 1){
        v = w0[((size_t)col*2 + (ci & 1))*49 + (ci >> 1)];
      } else {
        const float* wp = (col < split) ? (w0 + (size_t)col*Cin*KT)
                                        : (w1 + (size_t)(col - split)*Cin*KT);
        v = wp[(size_t)ci*KT + tap];
      }
    }
    short h = bf16bits(v);
    hi8[e] = h;
    lo8[e] = bf16bits(v - bf2f(h));
  }
  out[(size_t)blk*128 + lane]      = hi8;
  out[(size_t)blk*128 + 64 + lane] = lo8;
}

// ---- split-K reduce: val = p0 + p1 + bias, ACT, then per-MODE store ----
// MODE 0: fp32 out [HW][NP] (zr -> zrb). MODE 1: GRU -> netnF + netnS hi/lo.
// MODE 2: -> hi/lo planes [HW][2][NP] (fh1 -> t128S).
template<int ACT, int MODE>
__global__ void k_red(const float* __restrict__ part, int NP, int HW,
                      const float* __restrict__ bias,
                      float* __restrict__ outF, unsigned short* __restrict__ outS,
                      const float* __restrict__ ez, const float* __restrict__ eold)
{
  int i = blockIdx.x*256 + threadIdx.x;
  if (i >= HW*NP) return;
  int row = i / NP, col = i - row*NP;
  float val = part[i] + part[(size_t)HW*NP + i] + bias[col];
  if (ACT == 1) val = fmaxf(val, 0.f);
  if (ACT == 2) val = 1.f/(1.f + expf(-val));
  if (ACT == 3) val = tanhf(val);
  if constexpr (MODE == 0){
    outF[i] = val;
  } else if constexpr (MODE == 1){
    float zz = ez[(size_t)row*192 + col];
    val = (1.f - zz)*eold[(size_t)row*96 + col] + zz*val;
    outF[(size_t)row*96 + col] = val;
    split1(val, &outS[(size_t)row*192 + col], &outS[(size_t)row*192 + 96 + col]);
  } else {
    split1(val, &outS[(size_t)row*2*NP + col], &outS[(size_t)row*2*NP + NP + col]);
  }
}

// ---------------------------------------------------------------------------
// GEMM: static k-loop + XCD swizzle. KS>1: blockIdx.z picks tap half,
// EPI=4 stores raw fp32 partials [kz][HW][osF] (bias/act in k_red).
// ---------------------------------------------------------------------------
template<int KTW, int CH32, int FM, int ACT, int EPI, int NQ, int NF, int KS>
__global__ __launch_bounds__(256)
void k_fgemm(const unsigned short* __restrict__ A, int Cpad,
             const float* __restrict__ zr_, const float* __restrict__ net_,
             const float* __restrict__ coF,
             const short8* __restrict__ B, int nt16, const float* __restrict__ bias,
             float* __restrict__ outF, int osF, int ooF,
             unsigned short* __restrict__ outS, int CpadS, int ooS,
             int Cout, int H, int W,
             const float* __restrict__ ez, int ezs,
             const float* __restrict__ eold, int eos)
{
  constexpr int KT = KTW*KTW, P = KTW/2;
  constexpr int TPZ = (KS > 1) ? (KT + KS - 1)/KS : KT;
  int HW = H*W;
  int lane = threadIdx.x & 63;
  int kz = (KS > 1) ? (int)blockIdx.z : 0;
  int nb = gridDim.x*gridDim.y;
  int wg = xcd_swz(blockIdx.y*gridDim.x + blockIdx.x, nb);
  int by = wg % gridDim.y;
  int bx = wg / gridDim.y;
  int mt = bx*4 + (threadIdx.x >> 6);
  int ct0 = by*NF;
  int p = mt*16 + (lane & 15);
  int x = p % W, y = p / W;
  int kq = (lane >> 4)*8;

  f32x4 acc[NF];
  #pragma unroll
  for (int f = 0; f < NF; f++) acc[f] = f32x4{0.f,0.f,0.f,0.f};
  const short8 zero8 = short8{0,0,0,0,0,0,0,0};

  #pragma unroll
  for (int tt = 0; tt < TPZ; tt++){
    int tap = kz*TPZ + tt;
    if (KS > 1 && tap >= KT) break;
    int dx = tap % KTW - P, dy = tap / KTW - P;
    int xx = x + dx, yy = y + dy;
    bool ok = ((unsigned)xx < (unsigned)W) && ((unsigned)yy < (unsigned)H);
    int base = yy*W + xx;
    const unsigned short* arow = A + (size_t)base*2*Cpad;
    #pragma unroll
    for (int c = 0; c < CH32; c++){
      int kt = tap*CH32 + c;
      short8 ah = zero8, al = zero8;
      if constexpr (FM == 2){
        float vv[8];
        #pragma unroll
        for (int e = 0; e < 8; e++){
          int ci = c*32 + kq + e;
          float v = 0.f;
          if (ci < 98){
            int t7 = ci >> 1, jj = ci & 1;
            int ddx = t7 % 7 - 3, ddy = t7 / 7 - 3;
            int x2 = x + ddx, y2 = y + ddy;
            if ((unsigned)x2 < (unsigned)W && (unsigned)y2 < (unsigned)H)
              v = coF[(size_t)jj*HW + y2*W + x2] - (float)(jj ? y2 : x2);
          }
          vv[e] = v;
        }
        #pragma unroll
        for (int e = 0; e < 8; e++){
          short h = bf16bits(vv[e]);
          ah[e] = h;
          al[e] = bf16bits(vv[e] - bf2f(h));
        }
      } else if (NQ > 0 && c < NQ){
        if (ok){
          const float4* zp = (const float4*)(zr_ + (size_t)base*192 + 96 + c*32 + kq);
          const float4* np = (const float4*)(net_ + (size_t)base*96 + c*32 + kq);
          float4 z0 = zp[0], z1 = zp[1], n0 = np[0], n1 = np[1];
          float vv[8] = {z0.x*n0.x, z0.y*n0.y, z0.z*n0.z, z0.w*n0.w,
                         z1.x*n1.x, z1.y*n1.y, z1.z*n1.z, z1.w*n1.w};
          #pragma unroll
          for (int e = 0; e < 8; e++){
            short h = bf16bits(vv[e]);
            ah[e] = h;
            al[e] = bf16bits(vv[e] - bf2f(h));
          }
        }
      } else {
        if (ok){
          const unsigned short* ap = arow + c*32 + kq;
          ah = *(const short8*)ap;
          al = *(const short8*)(ap + Cpad);
        }
      }
      const short8* bp = B + ((size_t)kt*nt16 + ct0)*128 + lane;
      #pragma unroll
      for (int f = 0; f < NF; f++){
        short8 bh = bp[(size_t)f*128], bl = bp[(size_t)f*128 + 64];
        acc[f] = __builtin_amdgcn_mfma_f32_16x16x32_bf16(ah, bh, acc[f], 0, 0, 0);
        acc[f] = __builtin_amdgcn_mfma_f32_16x16x32_bf16(al, bh, acc[f], 0, 0, 0);
        acc[f] = __builtin_amdgcn_mfma_f32_16x16x32_bf16(ah, bl, acc[f], 0, 0, 0);
      }
    }
  }

  int rowb = mt*16 + ((lane >> 4) << 2);
  int colq = lane & 15;
  size_t pOff = (KS > 1) ? (size_t)kz*HW*osF : 0;
  #pragma unroll
  for (int f = 0; f < NF; f++){
    int col = (ct0 + f)*16 + colq;
    if (col < Cout){
      float bb = bias[col];
      #pragma unroll
      for (int r = 0; r < 4; r++){
        int row = rowb + r;
        if constexpr (EPI == 4){
          outF[pOff + (size_t)row*osF + ooF + col] = acc[f][r];
        } else {
          float val = acc[f][r] + bb;
          if (ACT == 1) val = fmaxf(val, 0.f);
          if (ACT == 2) val = 1.f/(1.f + expf(-val));
          if (ACT == 3) val = tanhf(val);
          if constexpr (EPI == 2){
            outF[(size_t)col*HW + row] += val;
          } else {
            if constexpr (EPI == 1){
              float zz = ez[(size_t)row*ezs + col];
              val = (1.f - zz)*eold[(size_t)row*eos + col] + zz*val;
            }
            if constexpr (EPI == 1 || EPI == 3)
              outF[(size_t)row*osF + ooF + col] = val;
            if constexpr (EPI == 0 || EPI == 1)
              split1(val, &outS[(size_t)row*2*CpadS + ooS + col],
                          &outS[(size_t)row*2*CpadS + CpadS + ooS + col]);
          }
        }
      }
    }
  }
}

extern "C" void kernel_launch(void* const* d_in, const int* in_sizes, int n_in,
                              void* d_out, int out_size, void* d_ws, size_t ws_size,
                              hipStream_t stream)
{
  (void)in_sizes; (void)n_in; (void)out_size; (void)ws_size;
  const float* f1s[3]    = {(const float*)d_in[0], (const float*)d_in[2], (const float*)d_in[4]};
  const float* f2s[3]    = {(const float*)d_in[1], (const float*)d_in[3], (const float*)d_in[5]};
  const float* net_in[3] = {(const float*)d_in[6], (const float*)d_in[8], (const float*)d_in[10]};
  const float* inp_in[3] = {(const float*)d_in[7], (const float*)d_in[9], (const float*)d_in[11]};
  const float* Wc1 = (const float*)d_in[12]; const float* bc1 = (const float*)d_in[13];
  const float* Wf1 = (const float*)d_in[14]; const float* bf1 = (const float*)d_in[15];
  const float* Wf2 = (const float*)d_in[16]; const float* bf2 = (const float*)d_in[17];
  const float* Wm  = (const float*)d_in[18]; const float* bm  = (const float*)d_in[19];
  const float* Wz  = (const float*)d_in[20]; const float* bz  = (const float*)d_in[21];
  const float* Wr  = (const float*)d_in[22]; const float* br  = (const float*)d_in[23];
  const float* Wq  = (const float*)d_in[24]; const float* bq  = (const float*)d_in[25];
  const float* Wh1 = (const float*)d_in[26]; const float* bh1 = (const float*)d_in[27];
  const float* Wh2 = (const float*)d_in[28]; const float* bh2 = (const float*)d_in[29];

  const int Hs[3] = {96, 48, 24};

  float* ws = (float*)d_ws;
  size_t off = 0;
  auto alloc = [&](size_t nfl)->float*{
    float* p = ws + off;
    off += (nfl + 3) & ~((size_t)3);
    return p;
  };

  float* f2l[3][4]; float* f1h[3]; float* netP[3][2]; float* coords[3];
  unsigned short* netS[3][2]; unsigned short* hxS[3];
  for (int si = 0; si < 3; si++){
    int H = Hs[si], HW = H*H;
    for (int l = 0; l < 4; l++) f2l[si][l] = alloc((size_t)(HW >> (2*l))*128);
    f1h[si]     = alloc((size_t)HW*128);
    netP[si][0] = alloc((size_t)HW*96);
    netP[si][1] = alloc((size_t)HW*96);
    netS[si][0] = (unsigned short*)alloc((size_t)HW*96);
    netS[si][1] = (unsigned short*)alloc((size_t)HW*96);
    hxS[si]     = (unsigned short*)alloc((size_t)HW*256);
    coords[si]  = alloc((size_t)2*HW);
  }
  const int HWm = 96*96;
  unsigned short* corrS = (unsigned short*)alloc((size_t)HWm*224);
  unsigned short* flo1S = (unsigned short*)alloc((size_t)HWm*64);
  unsigned short* cminS = (unsigned short*)alloc((size_t)HWm*128);
  unsigned short* t128S = (unsigned short*)alloc((size_t)HWm*128);
  float* zrb   = alloc((size_t)HWm*192);
  float* partP = alloc((size_t)2*HWm*192);   // split-K partials
  float* Bc1 = alloc((size_t)7*6*512);
  float* Bf1 = alloc((size_t)4*4*512);
  float* Bf2 = alloc((size_t)18*2*512);
  float* Bm  = alloc((size_t)36*6*512);
  float* Bzr = alloc((size_t)72*12*512);
  float* Bq  = alloc((size_t)72*6*512);
  float* Bh1 = alloc((size_t)27*8*512);
  float* Bh2 = alloc((size_t)36*1*512);
  float* bzr = alloc(192);

  #define NB(n) dim3((unsigned)nblk((n), 256))

  // ---- one-time B packs ----
  k_packb<<<NB(7*6*64),  256,0,stream>>>(Wc1, Wc1, 96, 96, 196, 1, 7, 0, (short8*)Bc1, 6, 7);
  k_packb<<<NB(4*4*64),  256,0,stream>>>(Wf1, Wf1, 64, 64,  98, 1, 4, 1, (short8*)Bf1, 4, 4);
  k_packb<<<NB(18*2*64), 256,0,stream>>>(Wf2, Wf2, 32, 32,  64, 9, 2, 0, (short8*)Bf2, 2, 18);
  k_packb<<<NB(36*6*64), 256,0,stream>>>(Wm,  Wm,  80, 80, 128, 9, 4, 0, (short8*)Bm,  6, 36);
  k_packb<<<NB(72*12*64),256,0,stream>>>(Wz,  Wr,  96, 192,242, 9, 8, 0, (short8*)Bzr, 12, 72);
  k_packb<<<NB(72*6*64), 256,0,stream>>>(Wq,  Wq,  96, 96, 242, 9, 8, 0, (short8*)Bq,  6, 72);
  k_packb<<<NB(27*8*64), 256,0,stream>>>(Wh1, Wh1,128, 128, 96, 9, 3, 0, (short8*)Bh1, 8, 27);
  k_packb<<<NB(36*1*64), 256,0,stream>>>(Wh2, Wh2,  2,   2,128, 9, 4, 0, (short8*)Bh2, 1, 36);
  k_cat2<<<dim3(1), 256, 0, stream>>>(bz, br, bzr, 96);

  // ---- per-scale init ----
  for (int si = 0; si < 3; si++){
    int H = Hs[si], HW = H*H;
    k_init_scale<<<NB(HW*176), 256,0,stream>>>(net_in[si], inp_in[si], netP[si][0],
                                               netS[si][0], hxS[si], coords[si], H, H);
    k_transpose2<<<NB(2*HW*128), 256,0,stream>>>(f2s[si], f1s[si], f2l[si][0], f1h[si], HW);
    for (int l = 1; l < 4; l++){
      int Hl = H >> l;
      k_pool_c4<<<NB(32*Hl*Hl*4), 256,0,stream>>>(f2l[si][l-1], f2l[si][l], Hl, Hl);
    }
  }

  int cur[3] = {0, 0, 0};
  const int seq[6] = {2, 2, 1, 1, 0, 0};
  for (int it = 0; it < 6; it++){
    int si = seq[it];
    int H = Hs[si], W = H, HW = H*W;
    int MT = HW/16;
    float s = (si == 0) ? 2.0f : ((si == 1) ? 4.0f : 8.0f);
    float* netcF = netP[si][cur[si]];
    float* netnF = netP[si][cur[si]^1];
    unsigned short* netcS = netS[si][cur[si]];
    unsigned short* netnS = netS[si][cur[si]^1];
    float* co = coords[si];
    unsigned short* hx = hxS[si];
    unsigned gx = (unsigned)(MT/4);
    bool big = (si == 0);

    k_corr4<<<dim3((unsigned)(HW/4)), 256,0,stream>>>(
        f1h[si], f2l[si][0], f2l[si][1], f2l[si][2], f2l[si][3], co,
        corrS, hx, netcS, H, W);

    // c1 (1x1, corrS -> cminS, relu)
    if (big) k_fgemm<1,7,0,1,0,0,3,1><<<dim3(gx,2), 256,0,stream>>>(corrS,224, nullptr,nullptr,nullptr,
        (short8*)Bc1, 6, bc1, nullptr,0,0, cminS,128,0, 96, H,W, nullptr,0, nullptr,0);
    else     k_fgemm<1,7,0,1,0,0,2,1><<<dim3(gx,3), 256,0,stream>>>(corrS,224, nullptr,nullptr,nullptr,
        (short8*)Bc1, 6, bc1, nullptr,0,0, cminS,128,0, 96, H,W, nullptr,0, nullptr,0);
    // f1 (7x7 flow-im2row -> flo1S, relu)
    k_fgemm<1,4,2,1,0,0,2,1><<<dim3(gx,2), 256,0,stream>>>(nullptr,0, nullptr,nullptr,co,
        (short8*)Bf1, 4, bf1, nullptr,0,0, flo1S,64,0, 64, H,W, nullptr,0, nullptr,0);
    // f2 (3x3, flo1S -> cminS[96..127], relu)
    k_fgemm<3,2,0,1,0,0,2,1><<<dim3(gx,1), 256,0,stream>>>(flo1S,64, nullptr,nullptr,nullptr,
        (short8*)Bf2, 2, bf2, nullptr,0,0, cminS,128,96, 32, H,W, nullptr,0, nullptr,0);
    // m (3x3, cminS -> hxS[160..239], relu)
    if (big) k_fgemm<3,4,0,1,0,0,3,1><<<dim3(gx,2), 256,0,stream>>>(cminS,128, nullptr,nullptr,nullptr,
        (short8*)Bm, 6, bm, nullptr,0,0, hx,256,160, 80, H,W, nullptr,0, nullptr,0);
    else     k_fgemm<3,4,0,1,0,0,2,1><<<dim3(gx,3), 256,0,stream>>>(cminS,128, nullptr,nullptr,nullptr,
        (short8*)Bm, 6, bm, nullptr,0,0, hx,256,160, 80, H,W, nullptr,0, nullptr,0);
    // zr (3x3, hxS -> zrb, sigmoid)
    if (big){
      k_fgemm<3,8,0,0,4,0,4,2><<<dim3(gx,3,2), 256,0,stream>>>(hx,256, nullptr,nullptr,nullptr,
          (short8*)Bzr, 12, bzr, partP,192,0, nullptr,0,0, 192, H,W, nullptr,0, nullptr,0);
      k_red<2,0><<<NB(HW*192), 256,0,stream>>>(partP, 192, HW, bzr, zrb, nullptr, nullptr, nullptr);
    } else {
      k_fgemm<3,8,0,2,3,0,2,1><<<dim3(gx,6), 256,0,stream>>>(hx,256, nullptr,nullptr,nullptr,
          (short8*)Bzr, 12, bzr, zrb,192,0, nullptr,0,0, 192, H,W, nullptr,0, nullptr,0);
    }
    // q (3x3, [r*net inline | hxS] -> GRU -> netn fp32 + hi/lo)
    if (big){
      k_fgemm<3,8,0,0,4,3,3,2><<<dim3(gx,2,2), 256,0,stream>>>(hx,256, zrb,netcF,nullptr,
          (short8*)Bq, 6, bq, partP,96,0, nullptr,0,0, 96, H,W, nullptr,0, nullptr,0);
      k_red<3,1><<<NB(HW*96), 256,0,stream>>>(partP, 96, HW, bq, netnF, netnS, zrb, netcF);
    } else {
      k_fgemm<3,8,0,3,1,3,2,1><<<dim3(gx,3), 256,0,stream>>>(hx,256, zrb,netcF,nullptr,
          (short8*)Bq, 6, bq, netnF,96,0, netnS,96,0, 96, H,W, zrb,192, netcF,96);
    }
    // fh1 (3x3, netnS -> t128S, relu)
    if (big){
      k_fgemm<3,3,0,0,4,0,4,2><<<dim3(gx,2,2), 256,0,stream>>>(netnS,96, nullptr,nullptr,nullptr,
          (short8*)Bh1, 8, bh1, partP,128,0, nullptr,0,0, 128, H,W, nullptr,0, nullptr,0);
      k_red<1,2><<<NB(HW*128), 256,0,stream>>>(partP, 128, HW, bh1, nullptr, t128S, nullptr, nullptr);
    } else {
      k_fgemm<3,3,0,1,0,0,2,1><<<dim3(gx,4), 256,0,stream>>>(netnS,96, nullptr,nullptr,nullptr,
          (short8*)Bh1, 8, bh1, nullptr,0,0, t128S,128,0, 128, H,W, nullptr,0, nullptr,0);
    }
    // fh2 (3x3, t128S -> coords CHW +=)
    k_fgemm<3,4,0,0,2,0,1,1><<<dim3(gx,1), 256,0,stream>>>(t128S,128, nullptr,nullptr,nullptr,
        (short8*)Bh2, 1, bh2, co,0,0, nullptr,0,0, 2, H,W, nullptr,0, nullptr,0);

    int Hf = (si > 0) ? Hs[si-1] : 0;
    float* conext = (si > 0) ? coords[si-1] : nullptr;
    k_upflow2<<<NB(2*192*192 + (Hf ? 2*Hf*Hf : 0)), 256,0,stream>>>(
        co, (float*)d_out + (size_t)it*2*192*192, H, W, s, conext, Hf);

    cur[si] ^= 1;
  }
  #undef NB
}

// Round 20
// 1268.616 us; speedup vs baseline: 1.1459x; 1.0115x over previous
//
#include <hip/hip_runtime.h>
#include <hip/hip_bf16.h>
#include <math.h>

// ---------------------------------------------------------------------------
// RAFT-small forward — round 20: r19 (best, 1283us) + level-per-wave corr4.
// corr4 was the last latency-serialized kernel: each wave walked 4 pyramid
// levels serially. Now block = 4 waves = 1 query; wave wv computes level wv
// (4x wave count, 1/4 critical path, bit-identical per-level math).
// Split-K GEMMs (zr/q/fh1 @96²) kept from r19.
// ---------------------------------------------------------------------------

typedef __attribute__((ext_vector_type(8))) short short8;
typedef __attribute__((ext_vector_type(4))) float f32x4;

static inline int nblk(int n, int b){ return (n + b - 1) / b; }

__device__ __forceinline__ short bf16bits(float v){
  __hip_bfloat16 h = __float2bfloat16(v);
  return *reinterpret_cast<short*>(&h);
}
__device__ __forceinline__ float bf2f(short s){
  unsigned u = ((unsigned)(unsigned short)s) << 16;
  return *reinterpret_cast<float*>(&u);
}
__device__ __forceinline__ void split1(float v, unsigned short* hi, unsigned short* lo){
  short h = bf16bits(v);
  *hi = (unsigned short)h;
  *lo = (unsigned short)bf16bits(v - bf2f(h));
}
// bijective XCD swizzle (m204)
__device__ __forceinline__ int xcd_swz(int bid, int n){
  int q = n >> 3, r = n & 7;
  int x = bid & 7, k = bid >> 3;
  return (x < r ? x*(q+1) : r*(q+1) + (x-r)*q) + k;
}

// ---- init ----
__global__ void k_init_scale(const float* __restrict__ net_in, const float* __restrict__ inp_in,
                             float* __restrict__ netP, unsigned short* __restrict__ netS,
                             unsigned short* __restrict__ hxS,
                             float* __restrict__ coords, int H, int W)
{
  int HW = H*W;
  int i = blockIdx.x*256 + threadIdx.x;
  if (i >= HW*176) return;
  int p = i / 176, c = i - p*176;
  if (c < 96){
    float t = tanhf(net_in[(size_t)c*HW + p]);
    netP[(size_t)p*96 + c] = t;
    split1(t, &netS[(size_t)p*192 + c], &netS[(size_t)p*192 + 96 + c]);
  } else if (c < 160){
    float r = fmaxf(inp_in[(size_t)(c-96)*HW + p], 0.f);
    split1(r, &hxS[(size_t)p*512 + c], &hxS[(size_t)p*512 + 256 + c]);
  } else if (c < 174){
    int col = 242 + (c - 160);
    hxS[(size_t)p*512 + col] = 0;
    hxS[(size_t)p*512 + 256 + col] = 0;
  } else if (c == 174){
    coords[p] = (float)(p % W);
  } else {
    coords[HW + p] = (float)(p / W);
  }
}
// f2 -> chunk-major [32][HW][4]; f1 -> [HW][128]
__global__ void k_transpose2(const float* __restrict__ f2, const float* __restrict__ f1,
                             float* __restrict__ f2c, float* __restrict__ f1h, int HW)
{
  int i = blockIdx.x*256 + threadIdx.x;
  int n = HW*128;
  if (i >= 2*n) return;
  if (i < n){
    int p = i >> 7, c = i & 127;
    f2c[((size_t)(c >> 2)*HW + p)*4 + (c & 3)] = f2[c*HW + p];
  } else {
    int k = i - n; int p = k >> 7, c = k & 127;
    f1h[k] = f1[c*HW + p];
  }
}
// 2x2 avg pool chunk-major
__global__ void k_pool_c4(const float* __restrict__ in, float* __restrict__ out, int H2, int W2){
  int i = blockIdx.x*256 + threadIdx.x;
  int HW2 = H2*W2;
  int n = 32*HW2*4;
  if (i >= n) return;
  int e = i & 3, rest = i >> 2;
  int p = rest % HW2, cc = rest / HW2;
  int ox = p % W2, oy = p / W2;
  int Win = 2*W2;
  size_t HWin = (size_t)(2*H2)*Win;
  const float* b = in + (cc*HWin + (size_t)(2*oy)*Win + 2*ox)*4 + e;
  out[i] = 0.25f*(b[0] + b[4] + b[(size_t)Win*4] + b[(size_t)Win*4 + 4]);
}
__global__ void k_cat2(const float* __restrict__ a, const float* __restrict__ b,
                       float* __restrict__ o, int n){
  int i = blockIdx.x*256 + threadIdx.x;
  if (i < 2*n) o[i] = (i < n) ? a[i] : b[i-n];
}

// ---- corr lookup: block = 1 query, wave wv = level wv; + hx fill ----
__global__ __launch_bounds__(256)
void k_corr4(const float* __restrict__ f1h,
             const float* __restrict__ l0, const float* __restrict__ l1,
             const float* __restrict__ l2, const float* __restrict__ l3,
             const float* __restrict__ coords,
             unsigned short* __restrict__ corrS,
             unsigned short* __restrict__ hxS,
             const unsigned short* __restrict__ netS,
             int H, int W)
{
  int HW = H*W;
  int wv = threadIdx.x >> 6, lane = threadIdx.x & 63;
  int q = blockIdx.x;
  __shared__ __align__(16) float sf1[128];
  if (threadIdx.x < 128) sf1[threadIdx.x] = f1h[(size_t)q*128 + threadIdx.x];
  __syncthreads();
  float x = coords[q], y = coords[HW + q];
  const float* const lv[4] = {l0, l1, l2, l3};
  int u = lane & 7, v = lane >> 3;
  int t = lane;
  int j = min(t / 7, 6), k = min(t % 7, 6);
  const float4* a = (const float4*)sf1;
  {
    int i = wv;
    int Wi = W >> i, Hi = H >> i;
    size_t HWi = (size_t)Wi*Hi;
    float sc = 1.0f / (float)(1 << i);
    float xs = x*sc, ys = y*sc;
    float fx = floorf(xs), fy = floorf(ys);
    float wx = xs - fx, wy = ys - fy;
    float xf = fx + (float)(u - 3);
    float yf = fy + (float)(v - 3);
    float d = 0.0f;
    if (xf >= 0.0f && xf <= (float)(Wi-1) && yf >= 0.0f && yf <= (float)(Hi-1)){
      const float4* b = (const float4*)lv[i] + ((size_t)((int)yf)*Wi + (int)xf);
      float a0 = 0.f, a1 = 0.f, a2 = 0.f, a3 = 0.f;
      #pragma unroll
      for (int kk = 0; kk < 32; kk += 4){
        float4 av0 = a[kk],   bv0 = b[(size_t)kk*HWi];
        float4 av1 = a[kk+1], bv1 = b[(size_t)(kk+1)*HWi];
        float4 av2 = a[kk+2], bv2 = b[(size_t)(kk+2)*HWi];
        float4 av3 = a[kk+3], bv3 = b[(size_t)(kk+3)*HWi];
        a0 = fmaf(av0.x,bv0.x, fmaf(av0.y,bv0.y, fmaf(av0.z,bv0.z, fmaf(av0.w,bv0.w, a0))));
        a1 = fmaf(av1.x,bv1.x, fmaf(av1.y,bv1.y, fmaf(av1.z,bv1.z, fmaf(av1.w,bv1.w, a1))));
        a2 = fmaf(av2.x,bv2.x, fmaf(av2.y,bv2.y, fmaf(av2.z,bv2.z, fmaf(av2.w,bv2.w, a2))));
        a3 = fmaf(av3.x,bv3.x, fmaf(av3.y,bv3.y, fmaf(av3.z,bv3.z, fmaf(av3.w,bv3.w, a3))));
      }
      d = (a0 + a1) + (a2 + a3);
    }
    float d00 = __shfl(d,  k   *8 + j);
    float d10 = __shfl(d,  k   *8 + j + 1);
    float d01 = __shfl(d, (k+1)*8 + j);
    float d11 = __shfl(d, (k+1)*8 + j + 1);
    if (t < 49){
      float val = ((1.f-wx)*(1.f-wy)*d00 + wx*(1.f-wy)*d10
                + (1.f-wx)*wy*d01 + wx*wy*d11) * 0.08838834764831845f;
      split1(val, &corrS[(size_t)q*448 + i*49 + t], &corrS[(size_t)q*448 + 224 + i*49 + t]);
    }
  }
  if (wv == 0 && lane < 28){
    corrS[(size_t)q*448 + 196 + lane] = 0;
    corrS[(size_t)q*448 + 224 + 196 + lane] = 0;
  }
  if (wv == 1){
    hxS[(size_t)q*512 + lane]       = netS[(size_t)q*192 + lane];
    hxS[(size_t)q*512 + 256 + lane] = netS[(size_t)q*192 + 96 + lane];
    if (lane < 32){
      hxS[(size_t)q*512 + 64 + lane]       = netS[(size_t)q*192 + 64 + lane];
      hxS[(size_t)q*512 + 256 + 64 + lane] = netS[(size_t)q*192 + 96 + 64 + lane];
    } else if (lane == 32){
      split1(x - (float)(q % W), &hxS[(size_t)q*512 + 240], &hxS[(size_t)q*512 + 256 + 240]);
    } else if (lane == 33){
      split1(y - (float)(q / W), &hxS[(size_t)q*512 + 241], &hxS[(size_t)q*512 + 256 + 241]);
    }
  }
}

// ---- combined upsampler (unchanged) ----
__global__ void k_upflow2(const float* __restrict__ cin, float* __restrict__ pred,
                          int Hin, int Win, float s,
                          float* __restrict__ conext, int Hf)
{
  int idx = blockIdx.x*256 + threadIdx.x;
  const int HWp = 192*192;
  int c, py, px, Hout, Wout;
  float n; int subtract; float* outp; size_t oidx;
  if (idx < 2*HWp){
    c = idx / HWp; int rem = idx - c*HWp; py = rem / 192; px = rem % 192;
    Hout = 192; Wout = 192; n = s; subtract = 1; outp = pred; oidx = idx;
  } else {
    int k2 = idx - 2*HWp;
    int HWf = Hf*Hf;
    if (Hf == 0 || k2 >= 2*HWf) return;
    c = k2 / HWf; int rem = k2 - c*HWf; py = rem / Hf; px = rem % Hf;
    Hout = Hf; Wout = Hf; n = 2.f; subtract = 0; outp = conext; oidx = k2;
  }
  float posy = (float)py * (float)(Hin-1) / (float)(Hout-1);
  float posx = (float)px * (float)(Win-1) / (float)(Wout-1);
  int iy = (int)floorf(posy); iy = max(0, min(iy, Hin-2));
  int ix = (int)floorf(posx); ix = max(0, min(ix, Win-2));
  float wy = posy - (float)iy, wx = posx - (float)ix;
  const float* base = cin + (size_t)c*Hin*Win;
  float s00 = 0.f, s10 = 0.f, s01 = 0.f, s11 = 0.f;
  if (subtract){
    if (c == 0){ s00 = (float)ix; s01 = (float)ix; s10 = (float)(ix+1); s11 = (float)(ix+1); }
    else       { s00 = (float)iy; s10 = (float)iy; s01 = (float)(iy+1); s11 = (float)(iy+1); }
  }
  float v00 = base[(size_t)iy*Win + ix]       - s00;
  float v10 = base[(size_t)iy*Win + ix + 1]   - s10;
  float v01 = base[(size_t)(iy+1)*Win + ix]   - s01;
  float v11 = base[(size_t)(iy+1)*Win + ix+1] - s11;
  float val = (1.f-wy)*((1.f-wx)*v00 + wx*v10) + wy*((1.f-wx)*v01 + wx*v11);
  outp[oidx] = n * val;
}

// ---- pack-B (unchanged) ----
__global__ void k_packb(const float* __restrict__ w0, const float* __restrict__ w1,
                        int split, int Cout, int Cin, int KT, int CH32, int mode,
                        short8* __restrict__ out, int nt16, int KTN)
{
  int gid = blockIdx.x*256 + threadIdx.x;
  if (gid >= KTN*nt16*64) return;
  int lane = gid & 63, blk = gid >> 6;
  int ct = blk % nt16, kt = blk / nt16;
  int col = ct*16 + (lane & 15);
  int tap = kt / CH32, chunk = kt - tap*CH32;
  int ci0 = chunk*32 + (lane >> 4)*8;
  short8 hi8, lo8;
  #pragma unroll
  for (int e = 0; e < 8; e++){
    int ci = ci0 + e;
    float v = 0.f;
    if (col < Cout && ci < Cin && tap < KT){
      if (mode == 1){
        v = w0[((size_t)col*2 + (ci & 1))*49 + (ci >> 1)];
      } else {
        const float* wp = (col < split) ? (w0 + (size_t)col*Cin*KT)
                                        : (w1 + (size_t)(col - split)*Cin*KT);
        v = wp[(size_t)ci*KT + tap];
      }
    }
    short h = bf16bits(v);
    hi8[e] = h;
    lo8[e] = bf16bits(v - bf2f(h));
  }
  out[(size_t)blk*128 + lane]      = hi8;
  out[(size_t)blk*128 + 64 + lane] = lo8;
}

// ---- split-K reduce (r19, unchanged) ----
template<int ACT, int MODE>
__global__ void k_red(const float* __restrict__ part, int NP, int HW,
                      const float* __restrict__ bias,
                      float* __restrict__ outF, unsigned short* __restrict__ outS,
                      const float* __restrict__ ez, const float* __restrict__ eold)
{
  int i = blockIdx.x*256 + threadIdx.x;
  if (i >= HW*NP) return;
  int row = i / NP, col = i - row*NP;
  float val = part[i] + part[(size_t)HW*NP + i] + bias[col];
  if (ACT == 1) val = fmaxf(val, 0.f);
  if (ACT == 2) val = 1.f/(1.f + expf(-val));
  if (ACT == 3) val = tanhf(val);
  if constexpr (MODE == 0){
    outF[i] = val;
  } else if constexpr (MODE == 1){
    float zz = ez[(size_t)row*192 + col];
    val = (1.f - zz)*eold[(size_t)row*96 + col] + zz*val;
    outF[(size_t)row*96 + col] = val;
    split1(val, &outS[(size_t)row*192 + col], &outS[(size_t)row*192 + 96 + col]);
  } else {
    split1(val, &outS[(size_t)row*2*NP + col], &outS[(size_t)row*2*NP + NP + col]);
  }
}

// ---------------------------------------------------------------------------
// GEMM (r19, unchanged): static k-loop + XCD swizzle + optional split-K.
// ---------------------------------------------------------------------------
template<int KTW, int CH32, int FM, int ACT, int EPI, int NQ, int NF, int KS>
__global__ __launch_bounds__(256)
void k_fgemm(const unsigned short* __restrict__ A, int Cpad,
             const float* __restrict__ zr_, const float* __restrict__ net_,
             const float* __restrict__ coF,
             const short8* __restrict__ B, int nt16, const float* __restrict__ bias,
             float* __restrict__ outF, int osF, int ooF,
             unsigned short* __restrict__ outS, int CpadS, int ooS,
             int Cout, int H, int W,
             const float* __restrict__ ez, int ezs,
             const float* __restrict__ eold, int eos)
{
  constexpr int KT = KTW*KTW, P = KTW/2;
  constexpr int TPZ = (KS > 1) ? (KT + KS - 1)/KS : KT;
  int HW = H*W;
  int lane = threadIdx.x & 63;
  int kz = (KS > 1) ? (int)blockIdx.z : 0;
  int nb = gridDim.x*gridDim.y;
  int wg = xcd_swz(blockIdx.y*gridDim.x + blockIdx.x, nb);
  int by = wg % gridDim.y;
  int bx = wg / gridDim.y;
  int mt = bx*4 + (threadIdx.x >> 6);
  int ct0 = by*NF;
  int p = mt*16 + (lane & 15);
  int x = p % W, y = p / W;
  int kq = (lane >> 4)*8;

  f32x4 acc[NF];
  #pragma unroll
  for (int f = 0; f < NF; f++) acc[f] = f32x4{0.f,0.f,0.f,0.f};
  const short8 zero8 = short8{0,0,0,0,0,0,0,0};

  #pragma unroll
  for (int tt = 0; tt < TPZ; tt++){
    int tap = kz*TPZ + tt;
    if (KS > 1 && tap >= KT) break;
    int dx = tap % KTW - P, dy = tap / KTW - P;
    int xx = x + dx, yy = y + dy;
    bool ok = ((unsigned)xx < (unsigned)W) && ((unsigned)yy < (unsigned)H);
    int base = yy*W + xx;
    const unsigned short* arow = A + (size_t)base*2*Cpad;
    #pragma unroll
    for (int c = 0; c < CH32; c++){
      int kt = tap*CH32 + c;
      short8 ah = zero8, al = zero8;
      if constexpr (FM == 2){
        float vv[8];
        #pragma unroll
        for (int e = 0; e < 8; e++){
          int ci = c*32 + kq + e;
          float v = 0.f;
          if (ci < 98){
            int t7 = ci >> 1, jj = ci & 1;
            int ddx = t7 % 7 - 3, ddy = t7 / 7 - 3;
            int x2 = x + ddx, y2 = y + ddy;
            if ((unsigned)x2 < (unsigned)W && (unsigned)y2 < (unsigned)H)
              v = coF[(size_t)jj*HW + y2*W + x2] - (float)(jj ? y2 : x2);
          }
          vv[e] = v;
        }
        #pragma unroll
        for (int e = 0; e < 8; e++){
          short h = bf16bits(vv[e]);
          ah[e] = h;
          al[e] = bf16bits(vv[e] - bf2f(h));
        }
      } else if (NQ > 0 && c < NQ){
        if (ok){
          const float4* zp = (const float4*)(zr_ + (size_t)base*192 + 96 + c*32 + kq);
          const float4* np = (const float4*)(net_ + (size_t)base*96 + c*32 + kq);
          float4 z0 = zp[0], z1 = zp[1], n0 = np[0], n1 = np[1];
          float vv[8] = {z0.x*n0.x, z0.y*n0.y, z0.z*n0.z, z0.w*n0.w,
                         z1.x*n1.x, z1.y*n1.y, z1.z*n1.z, z1.w*n1.w};
          #pragma unroll
          for (int e = 0; e < 8; e++){
            short h = bf16bits(vv[e]);
            ah[e] = h;
            al[e] = bf16bits(vv[e] - bf2f(h));
          }
        }
      } else {
        if (ok){
          const unsigned short* ap = arow + c*32 + kq;
          ah = *(const short8*)ap;
          al = *(const short8*)(ap + Cpad);
        }
      }
      const short8* bp = B + ((size_t)kt*nt16 + ct0)*128 + lane;
      #pragma unroll
      for (int f = 0; f < NF; f++){
        short8 bh = bp[(size_t)f*128], bl = bp[(size_t)f*128 + 64];
        acc[f] = __builtin_amdgcn_mfma_f32_16x16x32_bf16(ah, bh, acc[f], 0, 0, 0);
        acc[f] = __builtin_amdgcn_mfma_f32_16x16x32_bf16(al, bh, acc[f], 0, 0, 0);
        acc[f] = __builtin_amdgcn_mfma_f32_16x16x32_bf16(ah, bl, acc[f], 0, 0, 0);
      }
    }
  }

  int rowb = mt*16 + ((lane >> 4) << 2);
  int colq = lane & 15;
  size_t pOff = (KS > 1) ? (size_t)kz*HW*osF : 0;
  #pragma unroll
  for (int f = 0; f < NF; f++){
    int col = (ct0 + f)*16 + colq;
    if (col < Cout){
      float bb = bias[col];
      #pragma unroll
      for (int r = 0; r < 4; r++){
        int row = rowb + r;
        if constexpr (EPI == 4){
          outF[pOff + (size_t)row*osF + ooF + col] = acc[f][r];
        } else {
          float val = acc[f][r] + bb;
          if (ACT == 1) val = fmaxf(val, 0.f);
          if (ACT == 2) val = 1.f/(1.f + expf(-val));
          if (ACT == 3) val = tanhf(val);
          if constexpr (EPI == 2){
            outF[(size_t)col*HW + row] += val;
          } else {
            if constexpr (EPI == 1){
              float zz = ez[(size_t)row*ezs + col];
              val = (1.f - zz)*eold[(size_t)row*eos + col] + zz*val;
            }
            if constexpr (EPI == 1 || EPI == 3)
              outF[(size_t)row*osF + ooF + col] = val;
            if constexpr (EPI == 0 || EPI == 1)
              split1(val, &outS[(size_t)row*2*CpadS + ooS + col],
                          &outS[(size_t)row*2*CpadS + CpadS + ooS + col]);
          }
        }
      }
    }
  }
}

extern "C" void kernel_launch(void* const* d_in, const int* in_sizes, int n_in,
                              void* d_out, int out_size, void* d_ws, size_t ws_size,
                              hipStream_t stream)
{
  (void)in_sizes; (void)n_in; (void)out_size; (void)ws_size;
  const float* f1s[3]    = {(const float*)d_in[0], (const float*)d_in[2], (const float*)d_in[4]};
  const float* f2s[3]    = {(const float*)d_in[1], (const float*)d_in[3], (const float*)d_in[5]};
  const float* net_in[3] = {(const float*)d_in[6], (const float*)d_in[8], (const float*)d_in[10]};
  const float* inp_in[3] = {(const float*)d_in[7], (const float*)d_in[9], (const float*)d_in[11]};
  const float* Wc1 = (const float*)d_in[12]; const float* bc1 = (const float*)d_in[13];
  const float* Wf1 = (const float*)d_in[14]; const float* bf1 = (const float*)d_in[15];
  const float* Wf2 = (const float*)d_in[16]; const float* bf2 = (const float*)d_in[17];
  const float* Wm  = (const float*)d_in[18]; const float* bm  = (const float*)d_in[19];
  const float* Wz  = (const float*)d_in[20]; const float* bz  = (const float*)d_in[21];
  const float* Wr  = (const float*)d_in[22]; const float* br  = (const float*)d_in[23];
  const float* Wq  = (const float*)d_in[24]; const float* bq  = (const float*)d_in[25];
  const float* Wh1 = (const float*)d_in[26]; const float* bh1 = (const float*)d_in[27];
  const float* Wh2 = (const float*)d_in[28]; const float* bh2 = (const float*)d_in[29];

  const int Hs[3] = {96, 48, 24};

  float* ws = (float*)d_ws;
  size_t off = 0;
  auto alloc = [&](size_t nfl)->float*{
    float* p = ws + off;
    off += (nfl + 3) & ~((size_t)3);
    return p;
  };

  float* f2l[3][4]; float* f1h[3]; float* netP[3][2]; float* coords[3];
  unsigned short* netS[3][2]; unsigned short* hxS[3];
  for (int si = 0; si < 3; si++){
    int H = Hs[si], HW = H*H;
    for (int l = 0; l < 4; l++) f2l[si][l] = alloc((size_t)(HW >> (2*l))*128);
    f1h[si]     = alloc((size_t)HW*128);
    netP[si][0] = alloc((size_t)HW*96);
    netP[si][1] = alloc((size_t)HW*96);
    netS[si][0] = (unsigned short*)alloc((size_t)HW*96);
    netS[si][1] = (unsigned short*)alloc((size_t)HW*96);
    hxS[si]     = (unsigned short*)alloc((size_t)HW*256);
    coords[si]  = alloc((size_t)2*HW);
  }
  const int HWm = 96*96;
  unsigned short* corrS = (unsigned short*)alloc((size_t)HWm*224);
  unsigned short* flo1S = (unsigned short*)alloc((size_t)HWm*64);
  unsigned short* cminS = (unsigned short*)alloc((size_t)HWm*128);
  unsigned short* t128S = (unsigned short*)alloc((size_t)HWm*128);
  float* zrb   = alloc((size_t)HWm*192);
  float* partP = alloc((size_t)2*HWm*192);
  float* Bc1 = alloc((size_t)7*6*512);
  float* Bf1 = alloc((size_t)4*4*512);
  float* Bf2 = alloc((size_t)18*2*512);
  float* Bm  = alloc((size_t)36*6*512);
  float* Bzr = alloc((size_t)72*12*512);
  float* Bq  = alloc((size_t)72*6*512);
  float* Bh1 = alloc((size_t)27*8*512);
  float* Bh2 = alloc((size_t)36*1*512);
  float* bzr = alloc(192);

  #define NB(n) dim3((unsigned)nblk((n), 256))

  // ---- one-time B packs ----
  k_packb<<<NB(7*6*64),  256,0,stream>>>(Wc1, Wc1, 96, 96, 196, 1, 7, 0, (short8*)Bc1, 6, 7);
  k_packb<<<NB(4*4*64),  256,0,stream>>>(Wf1, Wf1, 64, 64,  98, 1, 4, 1, (short8*)Bf1, 4, 4);
  k_packb<<<NB(18*2*64), 256,0,stream>>>(Wf2, Wf2, 32, 32,  64, 9, 2, 0, (short8*)Bf2, 2, 18);
  k_packb<<<NB(36*6*64), 256,0,stream>>>(Wm,  Wm,  80, 80, 128, 9, 4, 0, (short8*)Bm,  6, 36);
  k_packb<<<NB(72*12*64),256,0,stream>>>(Wz,  Wr,  96, 192,242, 9, 8, 0, (short8*)Bzr, 12, 72);
  k_packb<<<NB(72*6*64), 256,0,stream>>>(Wq,  Wq,  96, 96, 242, 9, 8, 0, (short8*)Bq,  6, 72);
  k_packb<<<NB(27*8*64), 256,0,stream>>>(Wh1, Wh1,128, 128, 96, 9, 3, 0, (short8*)Bh1, 8, 27);
  k_packb<<<NB(36*1*64), 256,0,stream>>>(Wh2, Wh2,  2,   2,128, 9, 4, 0, (short8*)Bh2, 1, 36);
  k_cat2<<<dim3(1), 256, 0, stream>>>(bz, br, bzr, 96);

  // ---- per-scale init ----
  for (int si = 0; si < 3; si++){
    int H = Hs[si], HW = H*H;
    k_init_scale<<<NB(HW*176), 256,0,stream>>>(net_in[si], inp_in[si], netP[si][0],
                                               netS[si][0], hxS[si], coords[si], H, H);
    k_transpose2<<<NB(2*HW*128), 256,0,stream>>>(f2s[si], f1s[si], f2l[si][0], f1h[si], HW);
    for (int l = 1; l < 4; l++){
      int Hl = H >> l;
      k_pool_c4<<<NB(32*Hl*Hl*4), 256,0,stream>>>(f2l[si][l-1], f2l[si][l], Hl, Hl);
    }
  }

  int cur[3] = {0, 0, 0};
  const int seq[6] = {2, 2, 1, 1, 0, 0};
  for (int it = 0; it < 6; it++){
    int si = seq[it];
    int H = Hs[si], W = H, HW = H*W;
    int MT = HW/16;
    float s = (si == 0) ? 2.0f : ((si == 1) ? 4.0f : 8.0f);
    float* netcF = netP[si][cur[si]];
    float* netnF = netP[si][cur[si]^1];
    unsigned short* netcS = netS[si][cur[si]];
    unsigned short* netnS = netS[si][cur[si]^1];
    float* co = coords[si];
    unsigned short* hx = hxS[si];
    unsigned gx = (unsigned)(MT/4);
    bool big = (si == 0);

    // corr: one block per query, wave = level
    k_corr4<<<dim3((unsigned)HW), 256,0,stream>>>(
        f1h[si], f2l[si][0], f2l[si][1], f2l[si][2], f2l[si][3], co,
        corrS, hx, netcS, H, W);

    // c1 (1x1, corrS -> cminS, relu)
    if (big) k_fgemm<1,7,0,1,0,0,3,1><<<dim3(gx,2), 256,0,stream>>>(corrS,224, nullptr,nullptr,nullptr,
        (short8*)Bc1, 6, bc1, nullptr,0,0, cminS,128,0, 96, H,W, nullptr,0, nullptr,0);
    else     k_fgemm<1,7,0,1,0,0,2,1><<<dim3(gx,3), 256,0,stream>>>(corrS,224, nullptr,nullptr,nullptr,
        (short8*)Bc1, 6, bc1, nullptr,0,0, cminS,128,0, 96, H,W, nullptr,0, nullptr,0);
    // f1 (7x7 flow-im2row -> flo1S, relu)
    k_fgemm<1,4,2,1,0,0,2,1><<<dim3(gx,2), 256,0,stream>>>(nullptr,0, nullptr,nullptr,co,
        (short8*)Bf1, 4, bf1, nullptr,0,0, flo1S,64,0, 64, H,W, nullptr,0, nullptr,0);
    // f2 (3x3, flo1S -> cminS[96..127], relu)
    k_fgemm<3,2,0,1,0,0,2,1><<<dim3(gx,1), 256,0,stream>>>(flo1S,64, nullptr,nullptr,nullptr,
        (short8*)Bf2, 2, bf2, nullptr,0,0, cminS,128,96, 32, H,W, nullptr,0, nullptr,0);
    // m (3x3, cminS -> hxS[160..239], relu)
    if (big) k_fgemm<3,4,0,1,0,0,3,1><<<dim3(gx,2), 256,0,stream>>>(cminS,128, nullptr,nullptr,nullptr,
        (short8*)Bm, 6, bm, nullptr,0,0, hx,256,160, 80, H,W, nullptr,0, nullptr,0);
    else     k_fgemm<3,4,0,1,0,0,2,1><<<dim3(gx,3), 256,0,stream>>>(cminS,128, nullptr,nullptr,nullptr,
        (short8*)Bm, 6, bm, nullptr,0,0, hx,256,160, 80, H,W, nullptr,0, nullptr,0);
    // zr (3x3, hxS -> zrb, sigmoid)
    if (big){
      k_fgemm<3,8,0,0,4,0,4,2><<<dim3(gx,3,2), 256,0,stream>>>(hx,256, nullptr,nullptr,nullptr,
          (short8*)Bzr, 12, bzr, partP,192,0, nullptr,0,0, 192, H,W, nullptr,0, nullptr,0);
      k_red<2,0><<<NB(HW*192), 256,0,stream>>>(partP, 192, HW, bzr, zrb, nullptr, nullptr, nullptr);
    } else {
      k_fgemm<3,8,0,2,3,0,2,1><<<dim3(gx,6), 256,0,stream>>>(hx,256, nullptr,nullptr,nullptr,
          (short8*)Bzr, 12, bzr, zrb,192,0, nullptr,0,0, 192, H,W, nullptr,0, nullptr,0);
    }
    // q (3x3, [r*net inline | hxS] -> GRU -> netn fp32 + hi/lo)
    if (big){
      k_fgemm<3,8,0,0,4,3,3,2><<<dim3(gx,2,2), 256,0,stream>>>(hx,256, zrb,netcF,nullptr,
          (short8*)Bq, 6, bq, partP,96,0, nullptr,0,0, 96, H,W, nullptr,0, nullptr,0);
      k_red<3,1><<<NB(HW*96), 256,0,stream>>>(partP, 96, HW, bq, netnF, netnS, zrb, netcF);
    } else {
      k_fgemm<3,8,0,3,1,3,2,1><<<dim3(gx,3), 256,0,stream>>>(hx,256, zrb,netcF,nullptr,
          (short8*)Bq, 6, bq, netnF,96,0, netnS,96,0, 96, H,W, zrb,192, netcF,96);
    }
    // fh1 (3x3, netnS -> t128S, relu)
    if (big){
      k_fgemm<3,3,0,0,4,0,4,2><<<dim3(gx,2,2), 256,0,stream>>>(netnS,96, nullptr,nullptr,nullptr,
          (short8*)Bh1, 8, bh1, partP,128,0, nullptr,0,0, 128, H,W, nullptr,0, nullptr,0);
      k_red<1,2><<<NB(HW*128), 256,0,stream>>>(partP, 128, HW, bh1, nullptr, t128S, nullptr, nullptr);
    } else {
      k_fgemm<3,3,0,1,0,0,2,1><<<dim3(gx,4), 256,0,stream>>>(netnS,96, nullptr,nullptr,nullptr,
          (short8*)Bh1, 8, bh1, nullptr,0,0, t128S,128,0, 128, H,W, nullptr,0, nullptr,0);
    }
    // fh2 (3x3, t128S -> coords CHW +=)
    k_fgemm<3,4,0,0,2,0,1,1><<<dim3(gx,1), 256,0,stream>>>(t128S,128, nullptr,nullptr,nullptr,
        (short8*)Bh2, 1, bh2, co,0,0, nullptr,0,0, 2, H,W, nullptr,0, nullptr,0);

    int Hf = (si > 0) ? Hs[si-1] : 0;
    float* conext = (si > 0) ? coords[si-1] : nullptr;
    k_upflow2<<<NB(2*192*192 + (Hf ? 2*Hf*Hf : 0)), 256,0,stream>>>(
        co, (float*)d_out + (size_t)it*2*192*192, H, W, s, conext, Hf);

    cur[si] ^= 1;
  }
  #undef NB
}

// Round 21
// 1216.304 us; speedup vs baseline: 1.1952x; 1.0430x over previous
//
#include <hip/hip_runtime.h>
#include <hip/hip_bf16.h>
#include <math.h>

// ---------------------------------------------------------------------------
// RAFT-small forward — round 21: r20 (best, 1268us) + precomputed r*net planes.
// q's NQ inline path recomputed r*net (fp32 loads + 32 VALU cvt) per tap per
// column-pass (~6x redundant). Now zr's epilogue/reduce computes rnet once
// per (pixel,channel), stores hi/lo (same split1 of same fp32 product ->
// bit-identical MFMA inputs); q reads it as plain bf16 planes.
// ---------------------------------------------------------------------------

typedef __attribute__((ext_vector_type(8))) short short8;
typedef __attribute__((ext_vector_type(4))) float f32x4;

static inline int nblk(int n, int b){ return (n + b - 1) / b; }

__device__ __forceinline__ short bf16bits(float v){
  __hip_bfloat16 h = __float2bfloat16(v);
  return *reinterpret_cast<short*>(&h);
}
__device__ __forceinline__ float bf2f(short s){
  unsigned u = ((unsigned)(unsigned short)s) << 16;
  return *reinterpret_cast<float*>(&u);
}
__device__ __forceinline__ void split1(float v, unsigned short* hi, unsigned short* lo){
  short h = bf16bits(v);
  *hi = (unsigned short)h;
  *lo = (unsigned short)bf16bits(v - bf2f(h));
}
// bijective XCD swizzle (m204)
__device__ __forceinline__ int xcd_swz(int bid, int n){
  int q = n >> 3, r = n & 7;
  int x = bid & 7, k = bid >> 3;
  return (x < r ? x*(q+1) : r*(q+1) + (x-r)*q) + k;
}

// ---- init ----
__global__ void k_init_scale(const float* __restrict__ net_in, const float* __restrict__ inp_in,
                             float* __restrict__ netP, unsigned short* __restrict__ netS,
                             unsigned short* __restrict__ hxS,
                             float* __restrict__ coords, int H, int W)
{
  int HW = H*W;
  int i = blockIdx.x*256 + threadIdx.x;
  if (i >= HW*176) return;
  int p = i / 176, c = i - p*176;
  if (c < 96){
    float t = tanhf(net_in[(size_t)c*HW + p]);
    netP[(size_t)p*96 + c] = t;
    split1(t, &netS[(size_t)p*192 + c], &netS[(size_t)p*192 + 96 + c]);
  } else if (c < 160){
    float r = fmaxf(inp_in[(size_t)(c-96)*HW + p], 0.f);
    split1(r, &hxS[(size_t)p*512 + c], &hxS[(size_t)p*512 + 256 + c]);
  } else if (c < 174){
    int col = 242 + (c - 160);
    hxS[(size_t)p*512 + col] = 0;
    hxS[(size_t)p*512 + 256 + col] = 0;
  } else if (c == 174){
    coords[p] = (float)(p % W);
  } else {
    coords[HW + p] = (float)(p / W);
  }
}
// f2 -> chunk-major [32][HW][4]; f1 -> [HW][128]
__global__ void k_transpose2(const float* __restrict__ f2, const float* __restrict__ f1,
                             float* __restrict__ f2c, float* __restrict__ f1h, int HW)
{
  int i = blockIdx.x*256 + threadIdx.x;
  int n = HW*128;
  if (i >= 2*n) return;
  if (i < n){
    int p = i >> 7, c = i & 127;
    f2c[((size_t)(c >> 2)*HW + p)*4 + (c & 3)] = f2[c*HW + p];
  } else {
    int k = i - n; int p = k >> 7, c = k & 127;
    f1h[k] = f1[c*HW + p];
  }
}
// 2x2 avg pool chunk-major
__global__ void k_pool_c4(const float* __restrict__ in, float* __restrict__ out, int H2, int W2){
  int i = blockIdx.x*256 + threadIdx.x;
  int HW2 = H2*W2;
  int n = 32*HW2*4;
  if (i >= n) return;
  int e = i & 3, rest = i >> 2;
  int p = rest % HW2, cc = rest / HW2;
  int ox = p % W2, oy = p / W2;
  int Win = 2*W2;
  size_t HWin = (size_t)(2*H2)*Win;
  const float* b = in + (cc*HWin + (size_t)(2*oy)*Win + 2*ox)*4 + e;
  out[i] = 0.25f*(b[0] + b[4] + b[(size_t)Win*4] + b[(size_t)Win*4 + 4]);
}
__global__ void k_cat2(const float* __restrict__ a, const float* __restrict__ b,
                       float* __restrict__ o, int n){
  int i = blockIdx.x*256 + threadIdx.x;
  if (i < 2*n) o[i] = (i < n) ? a[i] : b[i-n];
}

// ---- corr lookup: block = 1 query, wave wv = level wv; + hx fill ----
__global__ __launch_bounds__(256)
void k_corr4(const float* __restrict__ f1h,
             const float* __restrict__ l0, const float* __restrict__ l1,
             const float* __restrict__ l2, const float* __restrict__ l3,
             const float* __restrict__ coords,
             unsigned short* __restrict__ corrS,
             unsigned short* __restrict__ hxS,
             const unsigned short* __restrict__ netS,
             int H, int W)
{
  int HW = H*W;
  int wv = threadIdx.x >> 6, lane = threadIdx.x & 63;
  int q = blockIdx.x;
  __shared__ __align__(16) float sf1[128];
  if (threadIdx.x < 128) sf1[threadIdx.x] = f1h[(size_t)q*128 + threadIdx.x];
  __syncthreads();
  float x = coords[q], y = coords[HW + q];
  const float* const lv[4] = {l0, l1, l2, l3};
  int u = lane & 7, v = lane >> 3;
  int t = lane;
  int j = min(t / 7, 6), k = min(t % 7, 6);
  const float4* a = (const float4*)sf1;
  {
    int i = wv;
    int Wi = W >> i, Hi = H >> i;
    size_t HWi = (size_t)Wi*Hi;
    float sc = 1.0f / (float)(1 << i);
    float xs = x*sc, ys = y*sc;
    float fx = floorf(xs), fy = floorf(ys);
    float wx = xs - fx, wy = ys - fy;
    float xf = fx + (float)(u - 3);
    float yf = fy + (float)(v - 3);
    float d = 0.0f;
    if (xf >= 0.0f && xf <= (float)(Wi-1) && yf >= 0.0f && yf <= (float)(Hi-1)){
      const float4* b = (const float4*)lv[i] + ((size_t)((int)yf)*Wi + (int)xf);
      float a0 = 0.f, a1 = 0.f, a2 = 0.f, a3 = 0.f;
      #pragma unroll
      for (int kk = 0; kk < 32; kk += 4){
        float4 av0 = a[kk],   bv0 = b[(size_t)kk*HWi];
        float4 av1 = a[kk+1], bv1 = b[(size_t)(kk+1)*HWi];
        float4 av2 = a[kk+2], bv2 = b[(size_t)(kk+2)*HWi];
        float4 av3 = a[kk+3], bv3 = b[(size_t)(kk+3)*HWi];
        a0 = fmaf(av0.x,bv0.x, fmaf(av0.y,bv0.y, fmaf(av0.z,bv0.z, fmaf(av0.w,bv0.w, a0))));
        a1 = fmaf(av1.x,bv1.x, fmaf(av1.y,bv1.y, fmaf(av1.z,bv1.z, fmaf(av1.w,bv1.w, a1))));
        a2 = fmaf(av2.x,bv2.x, fmaf(av2.y,bv2.y, fmaf(av2.z,bv2.z, fmaf(av2.w,bv2.w, a2))));
        a3 = fmaf(av3.x,bv3.x, fmaf(av3.y,bv3.y, fmaf(av3.z,bv3.z, fmaf(av3.w,bv3.w, a3))));
      }
      d = (a0 + a1) + (a2 + a3);
    }
    float d00 = __shfl(d,  k   *8 + j);
    float d10 = __shfl(d,  k   *8 + j + 1);
    float d01 = __shfl(d, (k+1)*8 + j);
    float d11 = __shfl(d, (k+1)*8 + j + 1);
    if (t < 49){
      float val = ((1.f-wx)*(1.f-wy)*d00 + wx*(1.f-wy)*d10
                + (1.f-wx)*wy*d01 + wx*wy*d11) * 0.08838834764831845f;
      split1(val, &corrS[(size_t)q*448 + i*49 + t], &corrS[(size_t)q*448 + 224 + i*49 + t]);
    }
  }
  if (wv == 0 && lane < 28){
    corrS[(size_t)q*448 + 196 + lane] = 0;
    corrS[(size_t)q*448 + 224 + 196 + lane] = 0;
  }
  if (wv == 1){
    hxS[(size_t)q*512 + lane]       = netS[(size_t)q*192 + lane];
    hxS[(size_t)q*512 + 256 + lane] = netS[(size_t)q*192 + 96 + lane];
    if (lane < 32){
      hxS[(size_t)q*512 + 64 + lane]       = netS[(size_t)q*192 + 64 + lane];
      hxS[(size_t)q*512 + 256 + 64 + lane] = netS[(size_t)q*192 + 96 + 64 + lane];
    } else if (lane == 32){
      split1(x - (float)(q % W), &hxS[(size_t)q*512 + 240], &hxS[(size_t)q*512 + 256 + 240]);
    } else if (lane == 33){
      split1(y - (float)(q / W), &hxS[(size_t)q*512 + 241], &hxS[(size_t)q*512 + 256 + 241]);
    }
  }
}

// ---- combined upsampler (unchanged) ----
__global__ void k_upflow2(const float* __restrict__ cin, float* __restrict__ pred,
                          int Hin, int Win, float s,
                          float* __restrict__ conext, int Hf)
{
  int idx = blockIdx.x*256 + threadIdx.x;
  const int HWp = 192*192;
  int c, py, px, Hout, Wout;
  float n; int subtract; float* outp; size_t oidx;
  if (idx < 2*HWp){
    c = idx / HWp; int rem = idx - c*HWp; py = rem / 192; px = rem % 192;
    Hout = 192; Wout = 192; n = s; subtract = 1; outp = pred; oidx = idx;
  } else {
    int k2 = idx - 2*HWp;
    int HWf = Hf*Hf;
    if (Hf == 0 || k2 >= 2*HWf) return;
    c = k2 / HWf; int rem = k2 - c*HWf; py = rem / Hf; px = rem % Hf;
    Hout = Hf; Wout = Hf; n = 2.f; subtract = 0; outp = conext; oidx = k2;
  }
  float posy = (float)py * (float)(Hin-1) / (float)(Hout-1);
  float posx = (float)px * (float)(Win-1) / (float)(Wout-1);
  int iy = (int)floorf(posy); iy = max(0, min(iy, Hin-2));
  int ix = (int)floorf(posx); ix = max(0, min(ix, Win-2));
  float wy = posy - (float)iy, wx = posx - (float)ix;
  const float* base = cin + (size_t)c*Hin*Win;
  float s00 = 0.f, s10 = 0.f, s01 = 0.f, s11 = 0.f;
  if (subtract){
    if (c == 0){ s00 = (float)ix; s01 = (float)ix; s10 = (float)(ix+1); s11 = (float)(ix+1); }
    else       { s00 = (float)iy; s10 = (float)iy; s01 = (float)(iy+1); s11 = (float)(iy+1); }
  }
  float v00 = base[(size_t)iy*Win + ix]       - s00;
  float v10 = base[(size_t)iy*Win + ix + 1]   - s10;
  float v01 = base[(size_t)(iy+1)*Win + ix]   - s01;
  float v11 = base[(size_t)(iy+1)*Win + ix+1] - s11;
  float val = (1.f-wy)*((1.f-wx)*v00 + wx*v10) + wy*((1.f-wx)*v01 + wx*v11);
  outp[oidx] = n * val;
}

// ---- pack-B (unchanged) ----
__global__ void k_packb(const float* __restrict__ w0, const float* __restrict__ w1,
                        int split, int Cout, int Cin, int KT, int CH32, int mode,
                        short8* __restrict__ out, int nt16, int KTN)
{
  int gid = blockIdx.x*256 + threadIdx.x;
  if (gid >= KTN*nt16*64) return;
  int lane = gid & 63, blk = gid >> 6;
  int ct = blk % nt16, kt = blk / nt16;
  int col = ct*16 + (lane & 15);
  int tap = kt / CH32, chunk = kt - tap*CH32;
  int ci0 = chunk*32 + (lane >> 4)*8;
  short8 hi8, lo8;
  #pragma unroll
  for (int e = 0; e < 8; e++){
    int ci = ci0 + e;
    float v = 0.f;
    if (col < Cout && ci < Cin && tap < KT){
      if (mode == 1){
        v = w0[((size_t)col*2 + (ci & 1))*49 + (ci >> 1)];
      } else {
        const float* wp = (col < split) ? (w0 + (size_t)col*Cin*KT)
                                        : (w1 + (size_t)(col - split)*Cin*KT);
        v = wp[(size_t)ci*KT + tap];
      }
    }
    short h = bf16bits(v);
    hi8[e] = h;
    lo8[e] = bf16bits(v - bf2f(h));
  }
  out[(size_t)blk*128 + lane]      = hi8;
  out[(size_t)blk*128 + 64 + lane] = lo8;
}

// ---- split-K reduce ----
// MODE 0: fp32 out. MODE 1: GRU -> netnF + netnS hi/lo. MODE 2: hi/lo planes.
// MODE 3: fp32 out (zrb) + rnet hi/lo for cols>=96 (rnet = val * eold[net]).
template<int ACT, int MODE>
__global__ void k_red(const float* __restrict__ part, int NP, int HW,
                      const float* __restrict__ bias,
                      float* __restrict__ outF, unsigned short* __restrict__ outS,
                      const float* __restrict__ ez, const float* __restrict__ eold)
{
  int i = blockIdx.x*256 + threadIdx.x;
  if (i >= HW*NP) return;
  int row = i / NP, col = i - row*NP;
  float val = part[i] + part[(size_t)HW*NP + i] + bias[col];
  if (ACT == 1) val = fmaxf(val, 0.f);
  if (ACT == 2) val = 1.f/(1.f + expf(-val));
  if (ACT == 3) val = tanhf(val);
  if constexpr (MODE == 0){
    outF[i] = val;
  } else if constexpr (MODE == 1){
    float zz = ez[(size_t)row*192 + col];
    val = (1.f - zz)*eold[(size_t)row*96 + col] + zz*val;
    outF[(size_t)row*96 + col] = val;
    split1(val, &outS[(size_t)row*192 + col], &outS[(size_t)row*192 + 96 + col]);
  } else if constexpr (MODE == 2){
    split1(val, &outS[(size_t)row*2*NP + col], &outS[(size_t)row*2*NP + NP + col]);
  } else {
    outF[i] = val;
    if (col >= 96){
      float rn = val * eold[(size_t)row*96 + (col - 96)];
      split1(rn, &outS[(size_t)row*192 + (col - 96)],
                 &outS[(size_t)row*192 + 96 + (col - 96)]);
    }
  }
}

// ---------------------------------------------------------------------------
// GEMM: static k-loop + XCD swizzle + optional split-K.
// NQ>0: chunks c<NQ read precomputed rnet hi/lo planes RN [HW][2][96].
// EPI: 0 hi/lo; 1 GRU; 2 add CHW; 3 fp32; 4 raw partials; 5 fp32 + rnet hi/lo.
// ---------------------------------------------------------------------------
template<int KTW, int CH32, int FM, int ACT, int EPI, int NQ, int NF, int KS>
__global__ __launch_bounds__(256)
void k_fgemm(const unsigned short* __restrict__ A, int Cpad,
             const unsigned short* __restrict__ RN,
             const float* __restrict__ coF,
             const short8* __restrict__ B, int nt16, const float* __restrict__ bias,
             float* __restrict__ outF, int osF, int ooF,
             unsigned short* __restrict__ outS, int CpadS, int ooS,
             int Cout, int H, int W,
             const float* __restrict__ ez, int ezs,
             const float* __restrict__ eold, int eos)
{
  constexpr int KT = KTW*KTW, P = KTW/2;
  constexpr int TPZ = (KS > 1) ? (KT + KS - 1)/KS : KT;
  int HW = H*W;
  int lane = threadIdx.x & 63;
  int kz = (KS > 1) ? (int)blockIdx.z : 0;
  int nb = gridDim.x*gridDim.y;
  int wg = xcd_swz(blockIdx.y*gridDim.x + blockIdx.x, nb);
  int by = wg % gridDim.y;
  int bx = wg / gridDim.y;
  int mt = bx*4 + (threadIdx.x >> 6);
  int ct0 = by*NF;
  int p = mt*16 + (lane & 15);
  int x = p % W, y = p / W;
  int kq = (lane >> 4)*8;

  f32x4 acc[NF];
  #pragma unroll
  for (int f = 0; f < NF; f++) acc[f] = f32x4{0.f,0.f,0.f,0.f};
  const short8 zero8 = short8{0,0,0,0,0,0,0,0};

  #pragma unroll
  for (int tt = 0; tt < TPZ; tt++){
    int tap = kz*TPZ + tt;
    if (KS > 1 && tap >= KT) break;
    int dx = tap % KTW - P, dy = tap / KTW - P;
    int xx = x + dx, yy = y + dy;
    bool ok = ((unsigned)xx < (unsigned)W) && ((unsigned)yy < (unsigned)H);
    int base = yy*W + xx;
    const unsigned short* arow = A + (size_t)base*2*Cpad;
    #pragma unroll
    for (int c = 0; c < CH32; c++){
      int kt = tap*CH32 + c;
      short8 ah = zero8, al = zero8;
      if constexpr (FM == 2){
        float vv[8];
        #pragma unroll
        for (int e = 0; e < 8; e++){
          int ci = c*32 + kq + e;
          float v = 0.f;
          if (ci < 98){
            int t7 = ci >> 1, jj = ci & 1;
            int ddx = t7 % 7 - 3, ddy = t7 / 7 - 3;
            int x2 = x + ddx, y2 = y + ddy;
            if ((unsigned)x2 < (unsigned)W && (unsigned)y2 < (unsigned)H)
              v = coF[(size_t)jj*HW + y2*W + x2] - (float)(jj ? y2 : x2);
          }
          vv[e] = v;
        }
        #pragma unroll
        for (int e = 0; e < 8; e++){
          short h = bf16bits(vv[e]);
          ah[e] = h;
          al[e] = bf16bits(vv[e] - bf2f(h));
        }
      } else if (NQ > 0 && c < NQ){
        if (ok){
          const unsigned short* rp = RN + (size_t)base*192 + c*32 + kq;
          ah = *(const short8*)rp;
          al = *(const short8*)(rp + 96);
        }
      } else {
        if (ok){
          const unsigned short* ap = arow + c*32 + kq;
          ah = *(const short8*)ap;
          al = *(const short8*)(ap + Cpad);
        }
      }
      const short8* bp = B + ((size_t)kt*nt16 + ct0)*128 + lane;
      #pragma unroll
      for (int f = 0; f < NF; f++){
        short8 bh = bp[(size_t)f*128], bl = bp[(size_t)f*128 + 64];
        acc[f] = __builtin_amdgcn_mfma_f32_16x16x32_bf16(ah, bh, acc[f], 0, 0, 0);
        acc[f] = __builtin_amdgcn_mfma_f32_16x16x32_bf16(al, bh, acc[f], 0, 0, 0);
        acc[f] = __builtin_amdgcn_mfma_f32_16x16x32_bf16(ah, bl, acc[f], 0, 0, 0);
      }
    }
  }

  int rowb = mt*16 + ((lane >> 4) << 2);
  int colq = lane & 15;
  size_t pOff = (KS > 1) ? (size_t)kz*HW*osF : 0;
  #pragma unroll
  for (int f = 0; f < NF; f++){
    int col = (ct0 + f)*16 + colq;
    if (col < Cout){
      float bb = bias[col];
      #pragma unroll
      for (int r = 0; r < 4; r++){
        int row = rowb + r;
        if constexpr (EPI == 4){
          outF[pOff + (size_t)row*osF + ooF + col] = acc[f][r];
        } else {
          float val = acc[f][r] + bb;
          if (ACT == 1) val = fmaxf(val, 0.f);
          if (ACT == 2) val = 1.f/(1.f + expf(-val));
          if (ACT == 3) val = tanhf(val);
          if constexpr (EPI == 2){
            outF[(size_t)col*HW + row] += val;
          } else if constexpr (EPI == 5){
            outF[(size_t)row*osF + col] = val;
            if (col >= 96){
              float rn = val * eold[(size_t)row*96 + (col - 96)];
              split1(rn, &outS[(size_t)row*192 + (col - 96)],
                         &outS[(size_t)row*192 + 96 + (col - 96)]);
            }
          } else {
            if constexpr (EPI == 1){
              float zz = ez[(size_t)row*ezs + col];
              val = (1.f - zz)*eold[(size_t)row*eos + col] + zz*val;
            }
            if constexpr (EPI == 1 || EPI == 3)
              outF[(size_t)row*osF + ooF + col] = val;
            if constexpr (EPI == 0 || EPI == 1)
              split1(val, &outS[(size_t)row*2*CpadS + ooS + col],
                          &outS[(size_t)row*2*CpadS + CpadS + ooS + col]);
          }
        }
      }
    }
  }
}

extern "C" void kernel_launch(void* const* d_in, const int* in_sizes, int n_in,
                              void* d_out, int out_size, void* d_ws, size_t ws_size,
                              hipStream_t stream)
{
  (void)in_sizes; (void)n_in; (void)out_size; (void)ws_size;
  const float* f1s[3]    = {(const float*)d_in[0], (const float*)d_in[2], (const float*)d_in[4]};
  const float* f2s[3]    = {(const float*)d_in[1], (const float*)d_in[3], (const float*)d_in[5]};
  const float* net_in[3] = {(const float*)d_in[6], (const float*)d_in[8], (const float*)d_in[10]};
  const float* inp_in[3] = {(const float*)d_in[7], (const float*)d_in[9], (const float*)d_in[11]};
  const float* Wc1 = (const float*)d_in[12]; const float* bc1 = (const float*)d_in[13];
  const float* Wf1 = (const float*)d_in[14]; const float* bf1 = (const float*)d_in[15];
  const float* Wf2 = (const float*)d_in[16]; const float* bf2 = (const float*)d_in[17];
  const float* Wm  = (const float*)d_in[18]; const float* bm  = (const float*)d_in[19];
  const float* Wz  = (const float*)d_in[20]; const float* bz  = (const float*)d_in[21];
  const float* Wr  = (const float*)d_in[22]; const float* br  = (const float*)d_in[23];
  const float* Wq  = (const float*)d_in[24]; const float* bq  = (const float*)d_in[25];
  const float* Wh1 = (const float*)d_in[26]; const float* bh1 = (const float*)d_in[27];
  const float* Wh2 = (const float*)d_in[28]; const float* bh2 = (const float*)d_in[29];

  const int Hs[3] = {96, 48, 24};

  float* ws = (float*)d_ws;
  size_t off = 0;
  auto alloc = [&](size_t nfl)->float*{
    float* p = ws + off;
    off += (nfl + 3) & ~((size_t)3);
    return p;
  };

  float* f2l[3][4]; float* f1h[3]; float* netP[3][2]; float* coords[3];
  unsigned short* netS[3][2]; unsigned short* hxS[3];
  for (int si = 0; si < 3; si++){
    int H = Hs[si], HW = H*H;
    for (int l = 0; l < 4; l++) f2l[si][l] = alloc((size_t)(HW >> (2*l))*128);
    f1h[si]     = alloc((size_t)HW*128);
    netP[si][0] = alloc((size_t)HW*96);
    netP[si][1] = alloc((size_t)HW*96);
    netS[si][0] = (unsigned short*)alloc((size_t)HW*96);
    netS[si][1] = (unsigned short*)alloc((size_t)HW*96);
    hxS[si]     = (unsigned short*)alloc((size_t)HW*256);
    coords[si]  = alloc((size_t)2*HW);
  }
  const int HWm = 96*96;
  unsigned short* corrS = (unsigned short*)alloc((size_t)HWm*224);
  unsigned short* flo1S = (unsigned short*)alloc((size_t)HWm*64);
  unsigned short* cminS = (unsigned short*)alloc((size_t)HWm*128);
  unsigned short* t128S = (unsigned short*)alloc((size_t)HWm*128);
  unsigned short* rnetS = (unsigned short*)alloc((size_t)HWm*96);
  float* zrb   = alloc((size_t)HWm*192);
  float* partP = alloc((size_t)2*HWm*192);
  float* Bc1 = alloc((size_t)7*6*512);
  float* Bf1 = alloc((size_t)4*4*512);
  float* Bf2 = alloc((size_t)18*2*512);
  float* Bm  = alloc((size_t)36*6*512);
  float* Bzr = alloc((size_t)72*12*512);
  float* Bq  = alloc((size_t)72*6*512);
  float* Bh1 = alloc((size_t)27*8*512);
  float* Bh2 = alloc((size_t)36*1*512);
  float* bzr = alloc(192);

  #define NB(n) dim3((unsigned)nblk((n), 256))

  // ---- one-time B packs ----
  k_packb<<<NB(7*6*64),  256,0,stream>>>(Wc1, Wc1, 96, 96, 196, 1, 7, 0, (short8*)Bc1, 6, 7);
  k_packb<<<NB(4*4*64),  256,0,stream>>>(Wf1, Wf1, 64, 64,  98, 1, 4, 1, (short8*)Bf1, 4, 4);
  k_packb<<<NB(18*2*64), 256,0,stream>>>(Wf2, Wf2, 32, 32,  64, 9, 2, 0, (short8*)Bf2, 2, 18);
  k_packb<<<NB(36*6*64), 256,0,stream>>>(Wm,  Wm,  80, 80, 128, 9, 4, 0, (short8*)Bm,  6, 36);
  k_packb<<<NB(72*12*64),256,0,stream>>>(Wz,  Wr,  96, 192,242, 9, 8, 0, (short8*)Bzr, 12, 72);
  k_packb<<<NB(72*6*64), 256,0,stream>>>(Wq,  Wq,  96, 96, 242, 9, 8, 0, (short8*)Bq,  6, 72);
  k_packb<<<NB(27*8*64), 256,0,stream>>>(Wh1, Wh1,128, 128, 96, 9, 3, 0, (short8*)Bh1, 8, 27);
  k_packb<<<NB(36*1*64), 256,0,stream>>>(Wh2, Wh2,  2,   2,128, 9, 4, 0, (short8*)Bh2, 1, 36);
  k_cat2<<<dim3(1), 256, 0, stream>>>(bz, br, bzr, 96);

  // ---- per-scale init ----
  for (int si = 0; si < 3; si++){
    int H = Hs[si], HW = H*H;
    k_init_scale<<<NB(HW*176), 256,0,stream>>>(net_in[si], inp_in[si], netP[si][0],
                                               netS[si][0], hxS[si], coords[si], H, H);
    k_transpose2<<<NB(2*HW*128), 256,0,stream>>>(f2s[si], f1s[si], f2l[si][0], f1h[si], HW);
    for (int l = 1; l < 4; l++){
      int Hl = H >> l;
      k_pool_c4<<<NB(32*Hl*Hl*4), 256,0,stream>>>(f2l[si][l-1], f2l[si][l], Hl, Hl);
    }
  }

  int cur[3] = {0, 0, 0};
  const int seq[6] = {2, 2, 1, 1, 0, 0};
  for (int it = 0; it < 6; it++){
    int si = seq[it];
    int H = Hs[si], W = H, HW = H*W;
    int MT = HW/16;
    float s = (si == 0) ? 2.0f : ((si == 1) ? 4.0f : 8.0f);
    float* netcF = netP[si][cur[si]];
    float* netnF = netP[si][cur[si]^1];
    unsigned short* netcS = netS[si][cur[si]];
    unsigned short* netnS = netS[si][cur[si]^1];
    float* co = coords[si];
    unsigned short* hx = hxS[si];
    unsigned gx = (unsigned)(MT/4);
    bool big = (si == 0);

    k_corr4<<<dim3((unsigned)HW), 256,0,stream>>>(
        f1h[si], f2l[si][0], f2l[si][1], f2l[si][2], f2l[si][3], co,
        corrS, hx, netcS, H, W);

    // c1 (1x1, corrS -> cminS, relu)
    if (big) k_fgemm<1,7,0,1,0,0,3,1><<<dim3(gx,2), 256,0,stream>>>(corrS,224, nullptr, nullptr,
        (short8*)Bc1, 6, bc1, nullptr,0,0, cminS,128,0, 96, H,W, nullptr,0, nullptr,0);
    else     k_fgemm<1,7,0,1,0,0,2,1><<<dim3(gx,3), 256,0,stream>>>(corrS,224, nullptr, nullptr,
        (short8*)Bc1, 6, bc1, nullptr,0,0, cminS,128,0, 96, H,W, nullptr,0, nullptr,0);
    // f1 (7x7 flow-im2row -> flo1S, relu)
    k_fgemm<1,4,2,1,0,0,2,1><<<dim3(gx,2), 256,0,stream>>>(nullptr,0, nullptr, co,
        (short8*)Bf1, 4, bf1, nullptr,0,0, flo1S,64,0, 64, H,W, nullptr,0, nullptr,0);
    // f2 (3x3, flo1S -> cminS[96..127], relu)
    k_fgemm<3,2,0,1,0,0,2,1><<<dim3(gx,1), 256,0,stream>>>(flo1S,64, nullptr, nullptr,
        (short8*)Bf2, 2, bf2, nullptr,0,0, cminS,128,96, 32, H,W, nullptr,0, nullptr,0);
    // m (3x3, cminS -> hxS[160..239], relu)
    if (big) k_fgemm<3,4,0,1,0,0,3,1><<<dim3(gx,2), 256,0,stream>>>(cminS,128, nullptr, nullptr,
        (short8*)Bm, 6, bm, nullptr,0,0, hx,256,160, 80, H,W, nullptr,0, nullptr,0);
    else     k_fgemm<3,4,0,1,0,0,2,1><<<dim3(gx,3), 256,0,stream>>>(cminS,128, nullptr, nullptr,
        (short8*)Bm, 6, bm, nullptr,0,0, hx,256,160, 80, H,W, nullptr,0, nullptr,0);
    // zr (3x3, hxS -> zrb sigmoid; + rnet hi/lo planes)
    if (big){
      k_fgemm<3,8,0,0,4,0,4,2><<<dim3(gx,3,2), 256,0,stream>>>(hx,256, nullptr, nullptr,
          (short8*)Bzr, 12, bzr, partP,192,0, nullptr,0,0, 192, H,W, nullptr,0, nullptr,0);
      k_red<2,3><<<NB(HW*192), 256,0,stream>>>(partP, 192, HW, bzr, zrb, rnetS, nullptr, netcF);
    } else {
      k_fgemm<3,8,0,2,5,0,2,1><<<dim3(gx,6), 256,0,stream>>>(hx,256, nullptr, nullptr,
          (short8*)Bzr, 12, bzr, zrb,192,0, rnetS,96,0, 192, H,W, nullptr,0, netcF,96);
    }
    // q (3x3, [rnetS | hxS] -> GRU -> netn fp32 + hi/lo)
    if (big){
      k_fgemm<3,8,0,0,4,3,3,2><<<dim3(gx,2,2), 256,0,stream>>>(hx,256, rnetS, nullptr,
          (short8*)Bq, 6, bq, partP,96,0, nullptr,0,0, 96, H,W, nullptr,0, nullptr,0);
      k_red<3,1><<<NB(HW*96), 256,0,stream>>>(partP, 96, HW, bq, netnF, netnS, zrb, netcF);
    } else {
      k_fgemm<3,8,0,3,1,3,2,1><<<dim3(gx,3), 256,0,stream>>>(hx,256, rnetS, nullptr,
          (short8*)Bq, 6, bq, netnF,96,0, netnS,96,0, 96, H,W, zrb,192, netcF,96);
    }
    // fh1 (3x3, netnS -> t128S, relu)
    if (big){
      k_fgemm<3,3,0,0,4,0,4,2><<<dim3(gx,2,2), 256,0,stream>>>(netnS,96, nullptr, nullptr,
          (short8*)Bh1, 8, bh1, partP,128,0, nullptr,0,0, 128, H,W, nullptr,0, nullptr,0);
      k_red<1,2><<<NB(HW*128), 256,0,stream>>>(partP, 128, HW, bh1, nullptr, t128S, nullptr, nullptr);
    } else {
      k_fgemm<3,3,0,1,0,0,2,1><<<dim3(gx,4), 256,0,stream>>>(netnS,96, nullptr, nullptr,
          (short8*)Bh1, 8, bh1, nullptr,0,0, t128S,128,0, 128, H,W, nullptr,0, nullptr,0);
    }
    // fh2 (3x3, t128S -> coords CHW +=)
    k_fgemm<3,4,0,0,2,0,1,1><<<dim3(gx,1), 256,0,stream>>>(t128S,128, nullptr, nullptr,
        (short8*)Bh2, 1, bh2, co,0,0, nullptr,0,0, 2, H,W, nullptr,0, nullptr,0);

    int Hf = (si > 0) ? Hs[si-1] : 0;
    float* conext = (si > 0) ? coords[si-1] : nullptr;
    k_upflow2<<<NB(2*192*192 + (Hf ? 2*Hf*Hf : 0)), 256,0,stream>>>(
        co, (float*)d_out + (size_t)it*2*192*192, H, W, s, conext, Hf);

    cur[si] ^= 1;
  }
  #undef NB
}

// Round 22
// 1190.161 us; speedup vs baseline: 1.2214x; 1.0220x over previous
//
#include <hip/hip_runtime.h>
#include <hip/hip_bf16.h>
#include <math.h>

// ---------------------------------------------------------------------------
// RAFT-small forward — round 22: r21 (best, 1216us); split-K=2 extended to
// the 48² zr/q/fh1 (they were the remaining block-starved dispatches:
// zr@48² had 144 blocks). Kernel code identical to r21; launcher-only change.
// ---------------------------------------------------------------------------

typedef __attribute__((ext_vector_type(8))) short short8;
typedef __attribute__((ext_vector_type(4))) float f32x4;

static inline int nblk(int n, int b){ return (n + b - 1) / b; }

__device__ __forceinline__ short bf16bits(float v){
  __hip_bfloat16 h = __float2bfloat16(v);
  return *reinterpret_cast<short*>(&h);
}
__device__ __forceinline__ float bf2f(short s){
  unsigned u = ((unsigned)(unsigned short)s) << 16;
  return *reinterpret_cast<float*>(&u);
}
__device__ __forceinline__ void split1(float v, unsigned short* hi, unsigned short* lo){
  short h = bf16bits(v);
  *hi = (unsigned short)h;
  *lo = (unsigned short)bf16bits(v - bf2f(h));
}
// bijective XCD swizzle (m204)
__device__ __forceinline__ int xcd_swz(int bid, int n){
  int q = n >> 3, r = n & 7;
  int x = bid & 7, k = bid >> 3;
  return (x < r ? x*(q+1) : r*(q+1) + (x-r)*q) + k;
}

// ---- init ----
__global__ void k_init_scale(const float* __restrict__ net_in, const float* __restrict__ inp_in,
                             float* __restrict__ netP, unsigned short* __restrict__ netS,
                             unsigned short* __restrict__ hxS,
                             float* __restrict__ coords, int H, int W)
{
  int HW = H*W;
  int i = blockIdx.x*256 + threadIdx.x;
  if (i >= HW*176) return;
  int p = i / 176, c = i - p*176;
  if (c < 96){
    float t = tanhf(net_in[(size_t)c*HW + p]);
    netP[(size_t)p*96 + c] = t;
    split1(t, &netS[(size_t)p*192 + c], &netS[(size_t)p*192 + 96 + c]);
  } else if (c < 160){
    float r = fmaxf(inp_in[(size_t)(c-96)*HW + p], 0.f);
    split1(r, &hxS[(size_t)p*512 + c], &hxS[(size_t)p*512 + 256 + c]);
  } else if (c < 174){
    int col = 242 + (c - 160);
    hxS[(size_t)p*512 + col] = 0;
    hxS[(size_t)p*512 + 256 + col] = 0;
  } else if (c == 174){
    coords[p] = (float)(p % W);
  } else {
    coords[HW + p] = (float)(p / W);
  }
}
// f2 -> chunk-major [32][HW][4]; f1 -> [HW][128]
__global__ void k_transpose2(const float* __restrict__ f2, const float* __restrict__ f1,
                             float* __restrict__ f2c, float* __restrict__ f1h, int HW)
{
  int i = blockIdx.x*256 + threadIdx.x;
  int n = HW*128;
  if (i >= 2*n) return;
  if (i < n){
    int p = i >> 7, c = i & 127;
    f2c[((size_t)(c >> 2)*HW + p)*4 + (c & 3)] = f2[c*HW + p];
  } else {
    int k = i - n; int p = k >> 7, c = k & 127;
    f1h[k] = f1[c*HW + p];
  }
}
// 2x2 avg pool chunk-major
__global__ void k_pool_c4(const float* __restrict__ in, float* __restrict__ out, int H2, int W2){
  int i = blockIdx.x*256 + threadIdx.x;
  int HW2 = H2*W2;
  int n = 32*HW2*4;
  if (i >= n) return;
  int e = i & 3, rest = i >> 2;
  int p = rest % HW2, cc = rest / HW2;
  int ox = p % W2, oy = p / W2;
  int Win = 2*W2;
  size_t HWin = (size_t)(2*H2)*Win;
  const float* b = in + (cc*HWin + (size_t)(2*oy)*Win + 2*ox)*4 + e;
  out[i] = 0.25f*(b[0] + b[4] + b[(size_t)Win*4] + b[(size_t)Win*4 + 4]);
}
__global__ void k_cat2(const float* __restrict__ a, const float* __restrict__ b,
                       float* __restrict__ o, int n){
  int i = blockIdx.x*256 + threadIdx.x;
  if (i < 2*n) o[i] = (i < n) ? a[i] : b[i-n];
}

// ---- corr lookup: block = 1 query, wave wv = level wv; + hx fill ----
__global__ __launch_bounds__(256)
void k_corr4(const float* __restrict__ f1h,
             const float* __restrict__ l0, const float* __restrict__ l1,
             const float* __restrict__ l2, const float* __restrict__ l3,
             const float* __restrict__ coords,
             unsigned short* __restrict__ corrS,
             unsigned short* __restrict__ hxS,
             const unsigned short* __restrict__ netS,
             int H, int W)
{
  int HW = H*W;
  int wv = threadIdx.x >> 6, lane = threadIdx.x & 63;
  int q = blockIdx.x;
  __shared__ __align__(16) float sf1[128];
  if (threadIdx.x < 128) sf1[threadIdx.x] = f1h[(size_t)q*128 + threadIdx.x];
  __syncthreads();
  float x = coords[q], y = coords[HW + q];
  const float* const lv[4] = {l0, l1, l2, l3};
  int u = lane & 7, v = lane >> 3;
  int t = lane;
  int j = min(t / 7, 6), k = min(t % 7, 6);
  const float4* a = (const float4*)sf1;
  {
    int i = wv;
    int Wi = W >> i, Hi = H >> i;
    size_t HWi = (size_t)Wi*Hi;
    float sc = 1.0f / (float)(1 << i);
    float xs = x*sc, ys = y*sc;
    float fx = floorf(xs), fy = floorf(ys);
    float wx = xs - fx, wy = ys - fy;
    float xf = fx + (float)(u - 3);
    float yf = fy + (float)(v - 3);
    float d = 0.0f;
    if (xf >= 0.0f && xf <= (float)(Wi-1) && yf >= 0.0f && yf <= (float)(Hi-1)){
      const float4* b = (const float4*)lv[i] + ((size_t)((int)yf)*Wi + (int)xf);
      float a0 = 0.f, a1 = 0.f, a2 = 0.f, a3 = 0.f;
      #pragma unroll
      for (int kk = 0; kk < 32; kk += 4){
        float4 av0 = a[kk],   bv0 = b[(size_t)kk*HWi];
        float4 av1 = a[kk+1], bv1 = b[(size_t)(kk+1)*HWi];
        float4 av2 = a[kk+2], bv2 = b[(size_t)(kk+2)*HWi];
        float4 av3 = a[kk+3], bv3 = b[(size_t)(kk+3)*HWi];
        a0 = fmaf(av0.x,bv0.x, fmaf(av0.y,bv0.y, fmaf(av0.z,bv0.z, fmaf(av0.w,bv0.w, a0))));
        a1 = fmaf(av1.x,bv1.x, fmaf(av1.y,bv1.y, fmaf(av1.z,bv1.z, fmaf(av1.w,bv1.w, a1))));
        a2 = fmaf(av2.x,bv2.x, fmaf(av2.y,bv2.y, fmaf(av2.z,bv2.z, fmaf(av2.w,bv2.w, a2))));
        a3 = fmaf(av3.x,bv3.x, fmaf(av3.y,bv3.y, fmaf(av3.z,bv3.z, fmaf(av3.w,bv3.w, a3))));
      }
      d = (a0 + a1) + (a2 + a3);
    }
    float d00 = __shfl(d,  k   *8 + j);
    float d10 = __shfl(d,  k   *8 + j + 1);
    float d01 = __shfl(d, (k+1)*8 + j);
    float d11 = __shfl(d, (k+1)*8 + j + 1);
    if (t < 49){
      float val = ((1.f-wx)*(1.f-wy)*d00 + wx*(1.f-wy)*d10
                + (1.f-wx)*wy*d01 + wx*wy*d11) * 0.08838834764831845f;
      split1(val, &corrS[(size_t)q*448 + i*49 + t], &corrS[(size_t)q*448 + 224 + i*49 + t]);
    }
  }
  if (wv == 0 && lane < 28){
    corrS[(size_t)q*448 + 196 + lane] = 0;
    corrS[(size_t)q*448 + 224 + 196 + lane] = 0;
  }
  if (wv == 1){
    hxS[(size_t)q*512 + lane]       = netS[(size_t)q*192 + lane];
    hxS[(size_t)q*512 + 256 + lane] = netS[(size_t)q*192 + 96 + lane];
    if (lane < 32){
      hxS[(size_t)q*512 + 64 + lane]       = netS[(size_t)q*192 + 64 + lane];
      hxS[(size_t)q*512 + 256 + 64 + lane] = netS[(size_t)q*192 + 96 + 64 + lane];
    } else if (lane == 32){
      split1(x - (float)(q % W), &hxS[(size_t)q*512 + 240], &hxS[(size_t)q*512 + 256 + 240]);
    } else if (lane == 33){
      split1(y - (float)(q / W), &hxS[(size_t)q*512 + 241], &hxS[(size_t)q*512 + 256 + 241]);
    }
  }
}

// ---- combined upsampler (unchanged) ----
__global__ void k_upflow2(const float* __restrict__ cin, float* __restrict__ pred,
                          int Hin, int Win, float s,
                          float* __restrict__ conext, int Hf)
{
  int idx = blockIdx.x*256 + threadIdx.x;
  const int HWp = 192*192;
  int c, py, px, Hout, Wout;
  float n; int subtract; float* outp; size_t oidx;
  if (idx < 2*HWp){
    c = idx / HWp; int rem = idx - c*HWp; py = rem / 192; px = rem % 192;
    Hout = 192; Wout = 192; n = s; subtract = 1; outp = pred; oidx = idx;
  } else {
    int k2 = idx - 2*HWp;
    int HWf = Hf*Hf;
    if (Hf == 0 || k2 >= 2*HWf) return;
    c = k2 / HWf; int rem = k2 - c*HWf; py = rem / Hf; px = rem % Hf;
    Hout = Hf; Wout = Hf; n = 2.f; subtract = 0; outp = conext; oidx = k2;
  }
  float posy = (float)py * (float)(Hin-1) / (float)(Hout-1);
  float posx = (float)px * (float)(Win-1) / (float)(Wout-1);
  int iy = (int)floorf(posy); iy = max(0, min(iy, Hin-2));
  int ix = (int)floorf(posx); ix = max(0, min(ix, Win-2));
  float wy = posy - (float)iy, wx = posx - (float)ix;
  const float* base = cin + (size_t)c*Hin*Win;
  float s00 = 0.f, s10 = 0.f, s01 = 0.f, s11 = 0.f;
  if (subtract){
    if (c == 0){ s00 = (float)ix; s01 = (float)ix; s10 = (float)(ix+1); s11 = (float)(ix+1); }
    else       { s00 = (float)iy; s10 = (float)iy; s01 = (float)(iy+1); s11 = (float)(iy+1); }
  }
  float v00 = base[(size_t)iy*Win + ix]       - s00;
  float v10 = base[(size_t)iy*Win + ix + 1]   - s10;
  float v01 = base[(size_t)(iy+1)*Win + ix]   - s01;
  float v11 = base[(size_t)(iy+1)*Win + ix+1] - s11;
  float val = (1.f-wy)*((1.f-wx)*v00 + wx*v10) + wy*((1.f-wx)*v01 + wx*v11);
  outp[oidx] = n * val;
}

// ---- pack-B (unchanged) ----
__global__ void k_packb(const float* __restrict__ w0, const float* __restrict__ w1,
                        int split, int Cout, int Cin, int KT, int CH32, int mode,
                        short8* __restrict__ out, int nt16, int KTN)
{
  int gid = blockIdx.x*256 + threadIdx.x;
  if (gid >= KTN*nt16*64) return;
  int lane = gid & 63, blk = gid >> 6;
  int ct = blk % nt16, kt = blk / nt16;
  int col = ct*16 + (lane & 15);
  int tap = kt / CH32, chunk = kt - tap*CH32;
  int ci0 = chunk*32 + (lane >> 4)*8;
  short8 hi8, lo8;
  #pragma unroll
  for (int e = 0; e < 8; e++){
    int ci = ci0 + e;
    float v = 0.f;
    if (col < Cout && ci < Cin && tap < KT){
      if (mode == 1){
        v = w0[((size_t)col*2 + (ci & 1))*49 + (ci >> 1)];
      } else {
        const float* wp = (col < split) ? (w0 + (size_t)col*Cin*KT)
                                        : (w1 + (size_t)(col - split)*Cin*KT);
        v = wp[(size_t)ci*KT + tap];
      }
    }
    short h = bf16bits(v);
    hi8[e] = h;
    lo8[e] = bf16bits(v - bf2f(h));
  }
  out[(size_t)blk*128 + lane]      = hi8;
  out[(size_t)blk*128 + 64 + lane] = lo8;
}

// ---- split-K reduce ----
// MODE 0: fp32 out. MODE 1: GRU -> netnF + netnS hi/lo. MODE 2: hi/lo planes.
// MODE 3: fp32 out (zrb) + rnet hi/lo for cols>=96.
template<int ACT, int MODE>
__global__ void k_red(const float* __restrict__ part, int NP, int HW,
                      const float* __restrict__ bias,
                      float* __restrict__ outF, unsigned short* __restrict__ outS,
                      const float* __restrict__ ez, const float* __restrict__ eold)
{
  int i = blockIdx.x*256 + threadIdx.x;
  if (i >= HW*NP) return;
  int row = i / NP, col = i - row*NP;
  float val = part[i] + part[(size_t)HW*NP + i] + bias[col];
  if (ACT == 1) val = fmaxf(val, 0.f);
  if (ACT == 2) val = 1.f/(1.f + expf(-val));
  if (ACT == 3) val = tanhf(val);
  if constexpr (MODE == 0){
    outF[i] = val;
  } else if constexpr (MODE == 1){
    float zz = ez[(size_t)row*192 + col];
    val = (1.f - zz)*eold[(size_t)row*96 + col] + zz*val;
    outF[(size_t)row*96 + col] = val;
    split1(val, &outS[(size_t)row*192 + col], &outS[(size_t)row*192 + 96 + col]);
  } else if constexpr (MODE == 2){
    split1(val, &outS[(size_t)row*2*NP + col], &outS[(size_t)row*2*NP + NP + col]);
  } else {
    outF[i] = val;
    if (col >= 96){
      float rn = val * eold[(size_t)row*96 + (col - 96)];
      split1(rn, &outS[(size_t)row*192 + (col - 96)],
                 &outS[(size_t)row*192 + 96 + (col - 96)]);
    }
  }
}

// ---------------------------------------------------------------------------
// GEMM (r21, unchanged): static k-loop + XCD swizzle + optional split-K.
// ---------------------------------------------------------------------------
template<int KTW, int CH32, int FM, int ACT, int EPI, int NQ, int NF, int KS>
__global__ __launch_bounds__(256)
void k_fgemm(const unsigned short* __restrict__ A, int Cpad,
             const unsigned short* __restrict__ RN,
             const float* __restrict__ coF,
             const short8* __restrict__ B, int nt16, const float* __restrict__ bias,
             float* __restrict__ outF, int osF, int ooF,
             unsigned short* __restrict__ outS, int CpadS, int ooS,
             int Cout, int H, int W,
             const float* __restrict__ ez, int ezs,
             const float* __restrict__ eold, int eos)
{
  constexpr int KT = KTW*KTW, P = KTW/2;
  constexpr int TPZ = (KS > 1) ? (KT + KS - 1)/KS : KT;
  int HW = H*W;
  int lane = threadIdx.x & 63;
  int kz = (KS > 1) ? (int)blockIdx.z : 0;
  int nb = gridDim.x*gridDim.y;
  int wg = xcd_swz(blockIdx.y*gridDim.x + blockIdx.x, nb);
  int by = wg % gridDim.y;
  int bx = wg / gridDim.y;
  int mt = bx*4 + (threadIdx.x >> 6);
  int ct0 = by*NF;
  int p = mt*16 + (lane & 15);
  int x = p % W, y = p / W;
  int kq = (lane >> 4)*8;

  f32x4 acc[NF];
  #pragma unroll
  for (int f = 0; f < NF; f++) acc[f] = f32x4{0.f,0.f,0.f,0.f};
  const short8 zero8 = short8{0,0,0,0,0,0,0,0};

  #pragma unroll
  for (int tt = 0; tt < TPZ; tt++){
    int tap = kz*TPZ + tt;
    if (KS > 1 && tap >= KT) break;
    int dx = tap % KTW - P, dy = tap / KTW - P;
    int xx = x + dx, yy = y + dy;
    bool ok = ((unsigned)xx < (unsigned)W) && ((unsigned)yy < (unsigned)H);
    int base = yy*W + xx;
    const unsigned short* arow = A + (size_t)base*2*Cpad;
    #pragma unroll
    for (int c = 0; c < CH32; c++){
      int kt = tap*CH32 + c;
      short8 ah = zero8, al = zero8;
      if constexpr (FM == 2){
        float vv[8];
        #pragma unroll
        for (int e = 0; e < 8; e++){
          int ci = c*32 + kq + e;
          float v = 0.f;
          if (ci < 98){
            int t7 = ci >> 1, jj = ci & 1;
            int ddx = t7 % 7 - 3, ddy = t7 / 7 - 3;
            int x2 = x + ddx, y2 = y + ddy;
            if ((unsigned)x2 < (unsigned)W && (unsigned)y2 < (unsigned)H)
              v = coF[(size_t)jj*HW + y2*W + x2] - (float)(jj ? y2 : x2);
          }
          vv[e] = v;
        }
        #pragma unroll
        for (int e = 0; e < 8; e++){
          short h = bf16bits(vv[e]);
          ah[e] = h;
          al[e] = bf16bits(vv[e] - bf2f(h));
        }
      } else if (NQ > 0 && c < NQ){
        if (ok){
          const unsigned short* rp = RN + (size_t)base*192 + c*32 + kq;
          ah = *(const short8*)rp;
          al = *(const short8*)(rp + 96);
        }
      } else {
        if (ok){
          const unsigned short* ap = arow + c*32 + kq;
          ah = *(const short8*)ap;
          al = *(const short8*)(ap + Cpad);
        }
      }
      const short8* bp = B + ((size_t)kt*nt16 + ct0)*128 + lane;
      #pragma unroll
      for (int f = 0; f < NF; f++){
        short8 bh = bp[(size_t)f*128], bl = bp[(size_t)f*128 + 64];
        acc[f] = __builtin_amdgcn_mfma_f32_16x16x32_bf16(ah, bh, acc[f], 0, 0, 0);
        acc[f] = __builtin_amdgcn_mfma_f32_16x16x32_bf16(al, bh, acc[f], 0, 0, 0);
        acc[f] = __builtin_amdgcn_mfma_f32_16x16x32_bf16(ah, bl, acc[f], 0, 0, 0);
      }
    }
  }

  int rowb = mt*16 + ((lane >> 4) << 2);
  int colq = lane & 15;
  size_t pOff = (KS > 1) ? (size_t)kz*HW*osF : 0;
  #pragma unroll
  for (int f = 0; f < NF; f++){
    int col = (ct0 + f)*16 + colq;
    if (col < Cout){
      float bb = bias[col];
      #pragma unroll
      for (int r = 0; r < 4; r++){
        int row = rowb + r;
        if constexpr (EPI == 4){
          outF[pOff + (size_t)row*osF + ooF + col] = acc[f][r];
        } else {
          float val = acc[f][r] + bb;
          if (ACT == 1) val = fmaxf(val, 0.f);
          if (ACT == 2) val = 1.f/(1.f + expf(-val));
          if (ACT == 3) val = tanhf(val);
          if constexpr (EPI == 2){
            outF[(size_t)col*HW + row] += val;
          } else if constexpr (EPI == 5){
            outF[(size_t)row*osF + col] = val;
            if (col >= 96){
              float rn = val * eold[(size_t)row*96 + (col - 96)];
              split1(rn, &outS[(size_t)row*192 + (col - 96)],
                         &outS[(size_t)row*192 + 96 + (col - 96)]);
            }
          } else {
            if constexpr (EPI == 1){
              float zz = ez[(size_t)row*ezs + col];
              val = (1.f - zz)*eold[(size_t)row*eos + col] + zz*val;
            }
            if constexpr (EPI == 1 || EPI == 3)
              outF[(size_t)row*osF + ooF + col] = val;
            if constexpr (EPI == 0 || EPI == 1)
              split1(val, &outS[(size_t)row*2*CpadS + ooS + col],
                          &outS[(size_t)row*2*CpadS + CpadS + ooS + col]);
          }
        }
      }
    }
  }
}

extern "C" void kernel_launch(void* const* d_in, const int* in_sizes, int n_in,
                              void* d_out, int out_size, void* d_ws, size_t ws_size,
                              hipStream_t stream)
{
  (void)in_sizes; (void)n_in; (void)out_size; (void)ws_size;
  const float* f1s[3]    = {(const float*)d_in[0], (const float*)d_in[2], (const float*)d_in[4]};
  const float* f2s[3]    = {(const float*)d_in[1], (const float*)d_in[3], (const float*)d_in[5]};
  const float* net_in[3] = {(const float*)d_in[6], (const float*)d_in[8], (const float*)d_in[10]};
  const float* inp_in[3] = {(const float*)d_in[7], (const float*)d_in[9], (const float*)d_in[11]};
  const float* Wc1 = (const float*)d_in[12]; const float* bc1 = (const float*)d_in[13];
  const float* Wf1 = (const float*)d_in[14]; const float* bf1 = (const float*)d_in[15];
  const float* Wf2 = (const float*)d_in[16]; const float* bf2 = (const float*)d_in[17];
  const float* Wm  = (const float*)d_in[18]; const float* bm  = (const float*)d_in[19];
  const float* Wz  = (const float*)d_in[20]; const float* bz  = (const float*)d_in[21];
  const float* Wr  = (const float*)d_in[22]; const float* br  = (const float*)d_in[23];
  const float* Wq  = (const float*)d_in[24]; const float* bq  = (const float*)d_in[25];
  const float* Wh1 = (const float*)d_in[26]; const float* bh1 = (const float*)d_in[27];
  const float* Wh2 = (const float*)d_in[28]; const float* bh2 = (const float*)d_in[29];

  const int Hs[3] = {96, 48, 24};

  float* ws = (float*)d_ws;
  size_t off = 0;
  auto alloc = [&](size_t nfl)->float*{
    float* p = ws + off;
    off += (nfl + 3) & ~((size_t)3);
    return p;
  };

  float* f2l[3][4]; float* f1h[3]; float* netP[3][2]; float* coords[3];
  unsigned short* netS[3][2]; unsigned short* hxS[3];
  for (int si = 0; si < 3; si++){
    int H = Hs[si], HW = H*H;
    for (int l = 0; l < 4; l++) f2l[si][l] = alloc((size_t)(HW >> (2*l))*128);
    f1h[si]     = alloc((size_t)HW*128);
    netP[si][0] = alloc((size_t)HW*96);
    netP[si][1] = alloc((size_t)HW*96);
    netS[si][0] = (unsigned short*)alloc((size_t)HW*96);
    netS[si][1] = (unsigned short*)alloc((size_t)HW*96);
    hxS[si]     = (unsigned short*)alloc((size_t)HW*256);
    coords[si]  = alloc((size_t)2*HW);
  }
  const int HWm = 96*96;
  unsigned short* corrS = (unsigned short*)alloc((size_t)HWm*224);
  unsigned short* flo1S = (unsigned short*)alloc((size_t)HWm*64);
  unsigned short* cminS = (unsigned short*)alloc((size_t)HWm*128);
  unsigned short* t128S = (unsigned short*)alloc((size_t)HWm*128);
  unsigned short* rnetS = (unsigned short*)alloc((size_t)HWm*96);
  float* zrb   = alloc((size_t)HWm*192);
  float* partP = alloc((size_t)2*HWm*192);
  float* Bc1 = alloc((size_t)7*6*512);
  float* Bf1 = alloc((size_t)4*4*512);
  float* Bf2 = alloc((size_t)18*2*512);
  float* Bm  = alloc((size_t)36*6*512);
  float* Bzr = alloc((size_t)72*12*512);
  float* Bq  = alloc((size_t)72*6*512);
  float* Bh1 = alloc((size_t)27*8*512);
  float* Bh2 = alloc((size_t)36*1*512);
  float* bzr = alloc(192);

  #define NB(n) dim3((unsigned)nblk((n), 256))

  // ---- one-time B packs ----
  k_packb<<<NB(7*6*64),  256,0,stream>>>(Wc1, Wc1, 96, 96, 196, 1, 7, 0, (short8*)Bc1, 6, 7);
  k_packb<<<NB(4*4*64),  256,0,stream>>>(Wf1, Wf1, 64, 64,  98, 1, 4, 1, (short8*)Bf1, 4, 4);
  k_packb<<<NB(18*2*64), 256,0,stream>>>(Wf2, Wf2, 32, 32,  64, 9, 2, 0, (short8*)Bf2, 2, 18);
  k_packb<<<NB(36*6*64), 256,0,stream>>>(Wm,  Wm,  80, 80, 128, 9, 4, 0, (short8*)Bm,  6, 36);
  k_packb<<<NB(72*12*64),256,0,stream>>>(Wz,  Wr,  96, 192,242, 9, 8, 0, (short8*)Bzr, 12, 72);
  k_packb<<<NB(72*6*64), 256,0,stream>>>(Wq,  Wq,  96, 96, 242, 9, 8, 0, (short8*)Bq,  6, 72);
  k_packb<<<NB(27*8*64), 256,0,stream>>>(Wh1, Wh1,128, 128, 96, 9, 3, 0, (short8*)Bh1, 8, 27);
  k_packb<<<NB(36*1*64), 256,0,stream>>>(Wh2, Wh2,  2,   2,128, 9, 4, 0, (short8*)Bh2, 1, 36);
  k_cat2<<<dim3(1), 256, 0, stream>>>(bz, br, bzr, 96);

  // ---- per-scale init ----
  for (int si = 0; si < 3; si++){
    int H = Hs[si], HW = H*H;
    k_init_scale<<<NB(HW*176), 256,0,stream>>>(net_in[si], inp_in[si], netP[si][0],
                                               netS[si][0], hxS[si], coords[si], H, H);
    k_transpose2<<<NB(2*HW*128), 256,0,stream>>>(f2s[si], f1s[si], f2l[si][0], f1h[si], HW);
    for (int l = 1; l < 4; l++){
      int Hl = H >> l;
      k_pool_c4<<<NB(32*Hl*Hl*4), 256,0,stream>>>(f2l[si][l-1], f2l[si][l], Hl, Hl);
    }
  }

  int cur[3] = {0, 0, 0};
  const int seq[6] = {2, 2, 1, 1, 0, 0};
  for (int it = 0; it < 6; it++){
    int si = seq[it];
    int H = Hs[si], W = H, HW = H*W;
    int MT = HW/16;
    float s = (si == 0) ? 2.0f : ((si == 1) ? 4.0f : 8.0f);
    float* netcF = netP[si][cur[si]];
    float* netnF = netP[si][cur[si]^1];
    unsigned short* netcS = netS[si][cur[si]];
    unsigned short* netnS = netS[si][cur[si]^1];
    float* co = coords[si];
    unsigned short* hx = hxS[si];
    unsigned gx = (unsigned)(MT/4);
    bool big = (si == 0);
    bool mid = (si == 1);

    k_corr4<<<dim3((unsigned)HW), 256,0,stream>>>(
        f1h[si], f2l[si][0], f2l[si][1], f2l[si][2], f2l[si][3], co,
        corrS, hx, netcS, H, W);

    // c1 (1x1, corrS -> cminS, relu)
    if (big) k_fgemm<1,7,0,1,0,0,3,1><<<dim3(gx,2), 256,0,stream>>>(corrS,224, nullptr, nullptr,
        (short8*)Bc1, 6, bc1, nullptr,0,0, cminS,128,0, 96, H,W, nullptr,0, nullptr,0);
    else     k_fgemm<1,7,0,1,0,0,2,1><<<dim3(gx,3), 256,0,stream>>>(corrS,224, nullptr, nullptr,
        (short8*)Bc1, 6, bc1, nullptr,0,0, cminS,128,0, 96, H,W, nullptr,0, nullptr,0);
    // f1 (7x7 flow-im2row -> flo1S, relu)
    k_fgemm<1,4,2,1,0,0,2,1><<<dim3(gx,2), 256,0,stream>>>(nullptr,0, nullptr, co,
        (short8*)Bf1, 4, bf1, nullptr,0,0, flo1S,64,0, 64, H,W, nullptr,0, nullptr,0);
    // f2 (3x3, flo1S -> cminS[96..127], relu)
    k_fgemm<3,2,0,1,0,0,2,1><<<dim3(gx,1), 256,0,stream>>>(flo1S,64, nullptr, nullptr,
        (short8*)Bf2, 2, bf2, nullptr,0,0, cminS,128,96, 32, H,W, nullptr,0, nullptr,0);
    // m (3x3, cminS -> hxS[160..239], relu)
    if (big) k_fgemm<3,4,0,1,0,0,3,1><<<dim3(gx,2), 256,0,stream>>>(cminS,128, nullptr, nullptr,
        (short8*)Bm, 6, bm, nullptr,0,0, hx,256,160, 80, H,W, nullptr,0, nullptr,0);
    else     k_fgemm<3,4,0,1,0,0,2,1><<<dim3(gx,3), 256,0,stream>>>(cminS,128, nullptr, nullptr,
        (short8*)Bm, 6, bm, nullptr,0,0, hx,256,160, 80, H,W, nullptr,0, nullptr,0);
    // zr (3x3, hxS -> zrb sigmoid; + rnet hi/lo planes)
    if (big){
      k_fgemm<3,8,0,0,4,0,4,2><<<dim3(gx,3,2), 256,0,stream>>>(hx,256, nullptr, nullptr,
          (short8*)Bzr, 12, bzr, partP,192,0, nullptr,0,0, 192, H,W, nullptr,0, nullptr,0);
      k_red<2,3><<<NB(HW*192), 256,0,stream>>>(partP, 192, HW, bzr, zrb, rnetS, nullptr, netcF);
    } else if (mid){
      k_fgemm<3,8,0,0,4,0,2,2><<<dim3(gx,6,2), 256,0,stream>>>(hx,256, nullptr, nullptr,
          (short8*)Bzr, 12, bzr, partP,192,0, nullptr,0,0, 192, H,W, nullptr,0, nullptr,0);
      k_red<2,3><<<NB(HW*192), 256,0,stream>>>(partP, 192, HW, bzr, zrb, rnetS, nullptr, netcF);
    } else {
      k_fgemm<3,8,0,2,5,0,2,1><<<dim3(gx,6), 256,0,stream>>>(hx,256, nullptr, nullptr,
          (short8*)Bzr, 12, bzr, zrb,192,0, rnetS,96,0, 192, H,W, nullptr,0, netcF,96);
    }
    // q (3x3, [rnetS | hxS] -> GRU -> netn fp32 + hi/lo)
    if (big){
      k_fgemm<3,8,0,0,4,3,3,2><<<dim3(gx,2,2), 256,0,stream>>>(hx,256, rnetS, nullptr,
          (short8*)Bq, 6, bq, partP,96,0, nullptr,0,0, 96, H,W, nullptr,0, nullptr,0);
      k_red<3,1><<<NB(HW*96), 256,0,stream>>>(partP, 96, HW, bq, netnF, netnS, zrb, netcF);
    } else if (mid){
      k_fgemm<3,8,0,0,4,3,2,2><<<dim3(gx,3,2), 256,0,stream>>>(hx,256, rnetS, nullptr,
          (short8*)Bq, 6, bq, partP,96,0, nullptr,0,0, 96, H,W, nullptr,0, nullptr,0);
      k_red<3,1><<<NB(HW*96), 256,0,stream>>>(partP, 96, HW, bq, netnF, netnS, zrb, netcF);
    } else {
      k_fgemm<3,8,0,3,1,3,2,1><<<dim3(gx,3), 256,0,stream>>>(hx,256, rnetS, nullptr,
          (short8*)Bq, 6, bq, netnF,96,0, netnS,96,0, 96, H,W, zrb,192, netcF,96);
    }
    // fh1 (3x3, netnS -> t128S, relu)
    if (big){
      k_fgemm<3,3,0,0,4,0,4,2><<<dim3(gx,2,2), 256,0,stream>>>(netnS,96, nullptr, nullptr,
          (short8*)Bh1, 8, bh1, partP,128,0, nullptr,0,0, 128, H,W, nullptr,0, nullptr,0);
      k_red<1,2><<<NB(HW*128), 256,0,stream>>>(partP, 128, HW, bh1, nullptr, t128S, nullptr, nullptr);
    } else if (mid){
      k_fgemm<3,3,0,0,4,0,2,2><<<dim3(gx,4,2), 256,0,stream>>>(netnS,96, nullptr, nullptr,
          (short8*)Bh1, 8, bh1, partP,128,0, nullptr,0,0, 128, H,W, nullptr,0, nullptr,0);
      k_red<1,2><<<NB(HW*128), 256,0,stream>>>(partP, 128, HW, bh1, nullptr, t128S, nullptr, nullptr);
    } else {
      k_fgemm<3,3,0,1,0,0,2,1><<<dim3(gx,4), 256,0,stream>>>(netnS,96, nullptr, nullptr,
          (short8*)Bh1, 8, bh1, nullptr,0,0, t128S,128,0, 128, H,W, nullptr,0, nullptr,0);
    }
    // fh2 (3x3, t128S -> coords CHW +=)
    k_fgemm<3,4,0,0,2,0,1,1><<<dim3(gx,1), 256,0,stream>>>(t128S,128, nullptr, nullptr,
        (short8*)Bh2, 1, bh2, co,0,0, nullptr,0,0, 2, H,W, nullptr,0, nullptr,0);

    int Hf = (si > 0) ? Hs[si-1] : 0;
    float* conext = (si > 0) ? coords[si-1] : nullptr;
    k_upflow2<<<NB(2*192*192 + (Hf ? 2*Hf*Hf : 0)), 256,0,stream>>>(
        co, (float*)d_out + (size_t)it*2*192*192, H, W, s, conext, Hf);

    cur[si] ^= 1;
  }
  #undef NB
}

// Round 23
// 1177.204 us; speedup vs baseline: 1.2349x; 1.0110x over previous
//
#include <hip/hip_runtime.h>
#include <hip/hip_bf16.h>
#include <math.h>

// ---------------------------------------------------------------------------
// RAFT-small forward — round 23: r22 (best, 1190us); KS=2 -> KS=3 on the
// heavy 96² GEMMs (zr/q/fh1). k_red gains a KS template param; partials
// buffer 3 slabs. 48² stays KS=2, 24² KS=1. Occupancy was the responding
// dial (26.7% at KS=2); split-K adds waves without duplicating A/B traffic.
// ---------------------------------------------------------------------------

typedef __attribute__((ext_vector_type(8))) short short8;
typedef __attribute__((ext_vector_type(4))) float f32x4;

static inline int nblk(int n, int b){ return (n + b - 1) / b; }

__device__ __forceinline__ short bf16bits(float v){
  __hip_bfloat16 h = __float2bfloat16(v);
  return *reinterpret_cast<short*>(&h);
}
__device__ __forceinline__ float bf2f(short s){
  unsigned u = ((unsigned)(unsigned short)s) << 16;
  return *reinterpret_cast<float*>(&u);
}
__device__ __forceinline__ void split1(float v, unsigned short* hi, unsigned short* lo){
  short h = bf16bits(v);
  *hi = (unsigned short)h;
  *lo = (unsigned short)bf16bits(v - bf2f(h));
}
// bijective XCD swizzle (m204)
__device__ __forceinline__ int xcd_swz(int bid, int n){
  int q = n >> 3, r = n & 7;
  int x = bid & 7, k = bid >> 3;
  return (x < r ? x*(q+1) : r*(q+1) + (x-r)*q) + k;
}

// ---- init ----
__global__ void k_init_scale(const float* __restrict__ net_in, const float* __restrict__ inp_in,
                             float* __restrict__ netP, unsigned short* __restrict__ netS,
                             unsigned short* __restrict__ hxS,
                             float* __restrict__ coords, int H, int W)
{
  int HW = H*W;
  int i = blockIdx.x*256 + threadIdx.x;
  if (i >= HW*176) return;
  int p = i / 176, c = i - p*176;
  if (c < 96){
    float t = tanhf(net_in[(size_t)c*HW + p]);
    netP[(size_t)p*96 + c] = t;
    split1(t, &netS[(size_t)p*192 + c], &netS[(size_t)p*192 + 96 + c]);
  } else if (c < 160){
    float r = fmaxf(inp_in[(size_t)(c-96)*HW + p], 0.f);
    split1(r, &hxS[(size_t)p*512 + c], &hxS[(size_t)p*512 + 256 + c]);
  } else if (c < 174){
    int col = 242 + (c - 160);
    hxS[(size_t)p*512 + col] = 0;
    hxS[(size_t)p*512 + 256 + col] = 0;
  } else if (c == 174){
    coords[p] = (float)(p % W);
  } else {
    coords[HW + p] = (float)(p / W);
  }
}
// f2 -> chunk-major [32][HW][4]; f1 -> [HW][128]
__global__ void k_transpose2(const float* __restrict__ f2, const float* __restrict__ f1,
                             float* __restrict__ f2c, float* __restrict__ f1h, int HW)
{
  int i = blockIdx.x*256 + threadIdx.x;
  int n = HW*128;
  if (i >= 2*n) return;
  if (i < n){
    int p = i >> 7, c = i & 127;
    f2c[((size_t)(c >> 2)*HW + p)*4 + (c & 3)] = f2[c*HW + p];
  } else {
    int k = i - n; int p = k >> 7, c = k & 127;
    f1h[k] = f1[c*HW + p];
  }
}
// 2x2 avg pool chunk-major
__global__ void k_pool_c4(const float* __restrict__ in, float* __restrict__ out, int H2, int W2){
  int i = blockIdx.x*256 + threadIdx.x;
  int HW2 = H2*W2;
  int n = 32*HW2*4;
  if (i >= n) return;
  int e = i & 3, rest = i >> 2;
  int p = rest % HW2, cc = rest / HW2;
  int ox = p % W2, oy = p / W2;
  int Win = 2*W2;
  size_t HWin = (size_t)(2*H2)*Win;
  const float* b = in + (cc*HWin + (size_t)(2*oy)*Win + 2*ox)*4 + e;
  out[i] = 0.25f*(b[0] + b[4] + b[(size_t)Win*4] + b[(size_t)Win*4 + 4]);
}
__global__ void k_cat2(const float* __restrict__ a, const float* __restrict__ b,
                       float* __restrict__ o, int n){
  int i = blockIdx.x*256 + threadIdx.x;
  if (i < 2*n) o[i] = (i < n) ? a[i] : b[i-n];
}

// ---- corr lookup: block = 1 query, wave wv = level wv; + hx fill ----
__global__ __launch_bounds__(256)
void k_corr4(const float* __restrict__ f1h,
             const float* __restrict__ l0, const float* __restrict__ l1,
             const float* __restrict__ l2, const float* __restrict__ l3,
             const float* __restrict__ coords,
             unsigned short* __restrict__ corrS,
             unsigned short* __restrict__ hxS,
             const unsigned short* __restrict__ netS,
             int H, int W)
{
  int HW = H*W;
  int wv = threadIdx.x >> 6, lane = threadIdx.x & 63;
  int q = blockIdx.x;
  __shared__ __align__(16) float sf1[128];
  if (threadIdx.x < 128) sf1[threadIdx.x] = f1h[(size_t)q*128 + threadIdx.x];
  __syncthreads();
  float x = coords[q], y = coords[HW + q];
  const float* const lv[4] = {l0, l1, l2, l3};
  int u = lane & 7, v = lane >> 3;
  int t = lane;
  int j = min(t / 7, 6), k = min(t % 7, 6);
  const float4* a = (const float4*)sf1;
  {
    int i = wv;
    int Wi = W >> i, Hi = H >> i;
    size_t HWi = (size_t)Wi*Hi;
    float sc = 1.0f / (float)(1 << i);
    float xs = x*sc, ys = y*sc;
    float fx = floorf(xs), fy = floorf(ys);
    float wx = xs - fx, wy = ys - fy;
    float xf = fx + (float)(u - 3);
    float yf = fy + (float)(v - 3);
    float d = 0.0f;
    if (xf >= 0.0f && xf <= (float)(Wi-1) && yf >= 0.0f && yf <= (float)(Hi-1)){
      const float4* b = (const float4*)lv[i] + ((size_t)((int)yf)*Wi + (int)xf);
      float a0 = 0.f, a1 = 0.f, a2 = 0.f, a3 = 0.f;
      #pragma unroll
      for (int kk = 0; kk < 32; kk += 4){
        float4 av0 = a[kk],   bv0 = b[(size_t)kk*HWi];
        float4 av1 = a[kk+1], bv1 = b[(size_t)(kk+1)*HWi];
        float4 av2 = a[kk+2], bv2 = b[(size_t)(kk+2)*HWi];
        float4 av3 = a[kk+3], bv3 = b[(size_t)(kk+3)*HWi];
        a0 = fmaf(av0.x,bv0.x, fmaf(av0.y,bv0.y, fmaf(av0.z,bv0.z, fmaf(av0.w,bv0.w, a0))));
        a1 = fmaf(av1.x,bv1.x, fmaf(av1.y,bv1.y, fmaf(av1.z,bv1.z, fmaf(av1.w,bv1.w, a1))));
        a2 = fmaf(av2.x,bv2.x, fmaf(av2.y,bv2.y, fmaf(av2.z,bv2.z, fmaf(av2.w,bv2.w, a2))));
        a3 = fmaf(av3.x,bv3.x, fmaf(av3.y,bv3.y, fmaf(av3.z,bv3.z, fmaf(av3.w,bv3.w, a3))));
      }
      d = (a0 + a1) + (a2 + a3);
    }
    float d00 = __shfl(d,  k   *8 + j);
    float d10 = __shfl(d,  k   *8 + j + 1);
    float d01 = __shfl(d, (k+1)*8 + j);
    float d11 = __shfl(d, (k+1)*8 + j + 1);
    if (t < 49){
      float val = ((1.f-wx)*(1.f-wy)*d00 + wx*(1.f-wy)*d10
                + (1.f-wx)*wy*d01 + wx*wy*d11) * 0.08838834764831845f;
      split1(val, &corrS[(size_t)q*448 + i*49 + t], &corrS[(size_t)q*448 + 224 + i*49 + t]);
    }
  }
  if (wv == 0 && lane < 28){
    corrS[(size_t)q*448 + 196 + lane] = 0;
    corrS[(size_t)q*448 + 224 + 196 + lane] = 0;
  }
  if (wv == 1){
    hxS[(size_t)q*512 + lane]       = netS[(size_t)q*192 + lane];
    hxS[(size_t)q*512 + 256 + lane] = netS[(size_t)q*192 + 96 + lane];
    if (lane < 32){
      hxS[(size_t)q*512 + 64 + lane]       = netS[(size_t)q*192 + 64 + lane];
      hxS[(size_t)q*512 + 256 + 64 + lane] = netS[(size_t)q*192 + 96 + 64 + lane];
    } else if (lane == 32){
      split1(x - (float)(q % W), &hxS[(size_t)q*512 + 240], &hxS[(size_t)q*512 + 256 + 240]);
    } else if (lane == 33){
      split1(y - (float)(q / W), &hxS[(size_t)q*512 + 241], &hxS[(size_t)q*512 + 256 + 241]);
    }
  }
}

// ---- combined upsampler (unchanged) ----
__global__ void k_upflow2(const float* __restrict__ cin, float* __restrict__ pred,
                          int Hin, int Win, float s,
                          float* __restrict__ conext, int Hf)
{
  int idx = blockIdx.x*256 + threadIdx.x;
  const int HWp = 192*192;
  int c, py, px, Hout, Wout;
  float n; int subtract; float* outp; size_t oidx;
  if (idx < 2*HWp){
    c = idx / HWp; int rem = idx - c*HWp; py = rem / 192; px = rem % 192;
    Hout = 192; Wout = 192; n = s; subtract = 1; outp = pred; oidx = idx;
  } else {
    int k2 = idx - 2*HWp;
    int HWf = Hf*Hf;
    if (Hf == 0 || k2 >= 2*HWf) return;
    c = k2 / HWf; int rem = k2 - c*HWf; py = rem / Hf; px = rem % Hf;
    Hout = Hf; Wout = Hf; n = 2.f; subtract = 0; outp = conext; oidx = k2;
  }
  float posy = (float)py * (float)(Hin-1) / (float)(Hout-1);
  float posx = (float)px * (float)(Win-1) / (float)(Wout-1);
  int iy = (int)floorf(posy); iy = max(0, min(iy, Hin-2));
  int ix = (int)floorf(posx); ix = max(0, min(ix, Win-2));
  float wy = posy - (float)iy, wx = posx - (float)ix;
  const float* base = cin + (size_t)c*Hin*Win;
  float s00 = 0.f, s10 = 0.f, s01 = 0.f, s11 = 0.f;
  if (subtract){
    if (c == 0){ s00 = (float)ix; s01 = (float)ix; s10 = (float)(ix+1); s11 = (float)(ix+1); }
    else       { s00 = (float)iy; s10 = (float)iy; s01 = (float)(iy+1); s11 = (float)(iy+1); }
  }
  float v00 = base[(size_t)iy*Win + ix]       - s00;
  float v10 = base[(size_t)iy*Win + ix + 1]   - s10;
  float v01 = base[(size_t)(iy+1)*Win + ix]   - s01;
  float v11 = base[(size_t)(iy+1)*Win + ix+1] - s11;
  float val = (1.f-wy)*((1.f-wx)*v00 + wx*v10) + wy*((1.f-wx)*v01 + wx*v11);
  outp[oidx] = n * val;
}

// ---- pack-B (unchanged) ----
__global__ void k_packb(const float* __restrict__ w0, const float* __restrict__ w1,
                        int split, int Cout, int Cin, int KT, int CH32, int mode,
                        short8* __restrict__ out, int nt16, int KTN)
{
  int gid = blockIdx.x*256 + threadIdx.x;
  if (gid >= KTN*nt16*64) return;
  int lane = gid & 63, blk = gid >> 6;
  int ct = blk % nt16, kt = blk / nt16;
  int col = ct*16 + (lane & 15);
  int tap = kt / CH32, chunk = kt - tap*CH32;
  int ci0 = chunk*32 + (lane >> 4)*8;
  short8 hi8, lo8;
  #pragma unroll
  for (int e = 0; e < 8; e++){
    int ci = ci0 + e;
    float v = 0.f;
    if (col < Cout && ci < Cin && tap < KT){
      if (mode == 1){
        v = w0[((size_t)col*2 + (ci & 1))*49 + (ci >> 1)];
      } else {
        const float* wp = (col < split) ? (w0 + (size_t)col*Cin*KT)
                                        : (w1 + (size_t)(col - split)*Cin*KT);
        v = wp[(size_t)ci*KT + tap];
      }
    }
    short h = bf16bits(v);
    hi8[e] = h;
    lo8[e] = bf16bits(v - bf2f(h));
  }
  out[(size_t)blk*128 + lane]      = hi8;
  out[(size_t)blk*128 + 64 + lane] = lo8;
}

// ---- split-K reduce (KS partials) ----
// MODE 0: fp32 out. MODE 1: GRU -> netnF + netnS hi/lo. MODE 2: hi/lo planes.
// MODE 3: fp32 out (zrb) + rnet hi/lo for cols>=96.
template<int ACT, int MODE, int KS>
__global__ void k_red(const float* __restrict__ part, int NP, int HW,
                      const float* __restrict__ bias,
                      float* __restrict__ outF, unsigned short* __restrict__ outS,
                      const float* __restrict__ ez, const float* __restrict__ eold)
{
  int i = blockIdx.x*256 + threadIdx.x;
  if (i >= HW*NP) return;
  int row = i / NP, col = i - row*NP;
  float val = part[i];
  #pragma unroll
  for (int s = 1; s < KS; s++) val += part[(size_t)s*HW*NP + i];
  val += bias[col];
  if (ACT == 1) val = fmaxf(val, 0.f);
  if (ACT == 2) val = 1.f/(1.f + expf(-val));
  if (ACT == 3) val = tanhf(val);
  if constexpr (MODE == 0){
    outF[i] = val;
  } else if constexpr (MODE == 1){
    float zz = ez[(size_t)row*192 + col];
    val = (1.f - zz)*eold[(size_t)row*96 + col] + zz*val;
    outF[(size_t)row*96 + col] = val;
    split1(val, &outS[(size_t)row*192 + col], &outS[(size_t)row*192 + 96 + col]);
  } else if constexpr (MODE == 2){
    split1(val, &outS[(size_t)row*2*NP + col], &outS[(size_t)row*2*NP + NP + col]);
  } else {
    outF[i] = val;
    if (col >= 96){
      float rn = val * eold[(size_t)row*96 + (col - 96)];
      split1(rn, &outS[(size_t)row*192 + (col - 96)],
                 &outS[(size_t)row*192 + 96 + (col - 96)]);
    }
  }
}

// ---------------------------------------------------------------------------
// GEMM (unchanged): static k-loop + XCD swizzle + optional split-K.
// ---------------------------------------------------------------------------
template<int KTW, int CH32, int FM, int ACT, int EPI, int NQ, int NF, int KS>
__global__ __launch_bounds__(256)
void k_fgemm(const unsigned short* __restrict__ A, int Cpad,
             const unsigned short* __restrict__ RN,
             const float* __restrict__ coF,
             const short8* __restrict__ B, int nt16, const float* __restrict__ bias,
             float* __restrict__ outF, int osF, int ooF,
             unsigned short* __restrict__ outS, int CpadS, int ooS,
             int Cout, int H, int W,
             const float* __restrict__ ez, int ezs,
             const float* __restrict__ eold, int eos)
{
  constexpr int KT = KTW*KTW, P = KTW/2;
  constexpr int TPZ = (KS > 1) ? (KT + KS - 1)/KS : KT;
  int HW = H*W;
  int lane = threadIdx.x & 63;
  int kz = (KS > 1) ? (int)blockIdx.z : 0;
  int nb = gridDim.x*gridDim.y;
  int wg = xcd_swz(blockIdx.y*gridDim.x + blockIdx.x, nb);
  int by = wg % gridDim.y;
  int bx = wg / gridDim.y;
  int mt = bx*4 + (threadIdx.x >> 6);
  int ct0 = by*NF;
  int p = mt*16 + (lane & 15);
  int x = p % W, y = p / W;
  int kq = (lane >> 4)*8;

  f32x4 acc[NF];
  #pragma unroll
  for (int f = 0; f < NF; f++) acc[f] = f32x4{0.f,0.f,0.f,0.f};
  const short8 zero8 = short8{0,0,0,0,0,0,0,0};

  #pragma unroll
  for (int tt = 0; tt < TPZ; tt++){
    int tap = kz*TPZ + tt;
    if (KS > 1 && tap >= KT) break;
    int dx = tap % KTW - P, dy = tap / KTW - P;
    int xx = x + dx, yy = y + dy;
    bool ok = ((unsigned)xx < (unsigned)W) && ((unsigned)yy < (unsigned)H);
    int base = yy*W + xx;
    const unsigned short* arow = A + (size_t)base*2*Cpad;
    #pragma unroll
    for (int c = 0; c < CH32; c++){
      int kt = tap*CH32 + c;
      short8 ah = zero8, al = zero8;
      if constexpr (FM == 2){
        float vv[8];
        #pragma unroll
        for (int e = 0; e < 8; e++){
          int ci = c*32 + kq + e;
          float v = 0.f;
          if (ci < 98){
            int t7 = ci >> 1, jj = ci & 1;
            int ddx = t7 % 7 - 3, ddy = t7 / 7 - 3;
            int x2 = x + ddx, y2 = y + ddy;
            if ((unsigned)x2 < (unsigned)W && (unsigned)y2 < (unsigned)H)
              v = coF[(size_t)jj*HW + y2*W + x2] - (float)(jj ? y2 : x2);
          }
          vv[e] = v;
        }
        #pragma unroll
        for (int e = 0; e < 8; e++){
          short h = bf16bits(vv[e]);
          ah[e] = h;
          al[e] = bf16bits(vv[e] - bf2f(h));
        }
      } else if (NQ > 0 && c < NQ){
        if (ok){
          const unsigned short* rp = RN + (size_t)base*192 + c*32 + kq;
          ah = *(const short8*)rp;
          al = *(const short8*)(rp + 96);
        }
      } else {
        if (ok){
          const unsigned short* ap = arow + c*32 + kq;
          ah = *(const short8*)ap;
          al = *(const short8*)(ap + Cpad);
        }
      }
      const short8* bp = B + ((size_t)kt*nt16 + ct0)*128 + lane;
      #pragma unroll
      for (int f = 0; f < NF; f++){
        short8 bh = bp[(size_t)f*128], bl = bp[(size_t)f*128 + 64];
        acc[f] = __builtin_amdgcn_mfma_f32_16x16x32_bf16(ah, bh, acc[f], 0, 0, 0);
        acc[f] = __builtin_amdgcn_mfma_f32_16x16x32_bf16(al, bh, acc[f], 0, 0, 0);
        acc[f] = __builtin_amdgcn_mfma_f32_16x16x32_bf16(ah, bl, acc[f], 0, 0, 0);
      }
    }
  }

  int rowb = mt*16 + ((lane >> 4) << 2);
  int colq = lane & 15;
  size_t pOff = (KS > 1) ? (size_t)kz*HW*osF : 0;
  #pragma unroll
  for (int f = 0; f < NF; f++){
    int col = (ct0 + f)*16 + colq;
    if (col < Cout){
      float bb = bias[col];
      #pragma unroll
      for (int r = 0; r < 4; r++){
        int row = rowb + r;
        if constexpr (EPI == 4){
          outF[pOff + (size_t)row*osF + ooF + col] = acc[f][r];
        } else {
          float val = acc[f][r] + bb;
          if (ACT == 1) val = fmaxf(val, 0.f);
          if (ACT == 2) val = 1.f/(1.f + expf(-val));
          if (ACT == 3) val = tanhf(val);
          if constexpr (EPI == 2){
            outF[(size_t)col*HW + row] += val;
          } else if constexpr (EPI == 5){
            outF[(size_t)row*osF + col] = val;
            if (col >= 96){
              float rn = val * eold[(size_t)row*96 + (col - 96)];
              split1(rn, &outS[(size_t)row*192 + (col - 96)],
                         &outS[(size_t)row*192 + 96 + (col - 96)]);
            }
          } else {
            if constexpr (EPI == 1){
              float zz = ez[(size_t)row*ezs + col];
              val = (1.f - zz)*eold[(size_t)row*eos + col] + zz*val;
            }
            if constexpr (EPI == 1 || EPI == 3)
              outF[(size_t)row*osF + ooF + col] = val;
            if constexpr (EPI == 0 || EPI == 1)
              split1(val, &outS[(size_t)row*2*CpadS + ooS + col],
                          &outS[(size_t)row*2*CpadS + CpadS + ooS + col]);
          }
        }
      }
    }
  }
}

extern "C" void kernel_launch(void* const* d_in, const int* in_sizes, int n_in,
                              void* d_out, int out_size, void* d_ws, size_t ws_size,
                              hipStream_t stream)
{
  (void)in_sizes; (void)n_in; (void)out_size; (void)ws_size;
  const float* f1s[3]    = {(const float*)d_in[0], (const float*)d_in[2], (const float*)d_in[4]};
  const float* f2s[3]    = {(const float*)d_in[1], (const float*)d_in[3], (const float*)d_in[5]};
  const float* net_in[3] = {(const float*)d_in[6], (const float*)d_in[8], (const float*)d_in[10]};
  const float* inp_in[3] = {(const float*)d_in[7], (const float*)d_in[9], (const float*)d_in[11]};
  const float* Wc1 = (const float*)d_in[12]; const float* bc1 = (const float*)d_in[13];
  const float* Wf1 = (const float*)d_in[14]; const float* bf1 = (const float*)d_in[15];
  const float* Wf2 = (const float*)d_in[16]; const float* bf2 = (const float*)d_in[17];
  const float* Wm  = (const float*)d_in[18]; const float* bm  = (const float*)d_in[19];
  const float* Wz  = (const float*)d_in[20]; const float* bz  = (const float*)d_in[21];
  const float* Wr  = (const float*)d_in[22]; const float* br  = (const float*)d_in[23];
  const float* Wq  = (const float*)d_in[24]; const float* bq  = (const float*)d_in[25];
  const float* Wh1 = (const float*)d_in[26]; const float* bh1 = (const float*)d_in[27];
  const float* Wh2 = (const float*)d_in[28]; const float* bh2 = (const float*)d_in[29];

  const int Hs[3] = {96, 48, 24};

  float* ws = (float*)d_ws;
  size_t off = 0;
  auto alloc = [&](size_t nfl)->float*{
    float* p = ws + off;
    off += (nfl + 3) & ~((size_t)3);
    return p;
  };

  float* f2l[3][4]; float* f1h[3]; float* netP[3][2]; float* coords[3];
  unsigned short* netS[3][2]; unsigned short* hxS[3];
  for (int si = 0; si < 3; si++){
    int H = Hs[si], HW = H*H;
    for (int l = 0; l < 4; l++) f2l[si][l] = alloc((size_t)(HW >> (2*l))*128);
    f1h[si]     = alloc((size_t)HW*128);
    netP[si][0] = alloc((size_t)HW*96);
    netP[si][1] = alloc((size_t)HW*96);
    netS[si][0] = (unsigned short*)alloc((size_t)HW*96);
    netS[si][1] = (unsigned short*)alloc((size_t)HW*96);
    hxS[si]     = (unsigned short*)alloc((size_t)HW*256);
    coords[si]  = alloc((size_t)2*HW);
  }
  const int HWm = 96*96;
  unsigned short* corrS = (unsigned short*)alloc((size_t)HWm*224);
  unsigned short* flo1S = (unsigned short*)alloc((size_t)HWm*64);
  unsigned short* cminS = (unsigned short*)alloc((size_t)HWm*128);
  unsigned short* t128S = (unsigned short*)alloc((size_t)HWm*128);
  unsigned short* rnetS = (unsigned short*)alloc((size_t)HWm*96);
  float* zrb   = alloc((size_t)HWm*192);
  float* partP = alloc((size_t)3*HWm*192);
  float* Bc1 = alloc((size_t)7*6*512);
  float* Bf1 = alloc((size_t)4*4*512);
  float* Bf2 = alloc((size_t)18*2*512);
  float* Bm  = alloc((size_t)36*6*512);
  float* Bzr = alloc((size_t)72*12*512);
  float* Bq  = alloc((size_t)72*6*512);
  float* Bh1 = alloc((size_t)27*8*512);
  float* Bh2 = alloc((size_t)36*1*512);
  float* bzr = alloc(192);

  #define NB(n) dim3((unsigned)nblk((n), 256))

  // ---- one-time B packs ----
  k_packb<<<NB(7*6*64),  256,0,stream>>>(Wc1, Wc1, 96, 96, 196, 1, 7, 0, (short8*)Bc1, 6, 7);
  k_packb<<<NB(4*4*64),  256,0,stream>>>(Wf1, Wf1, 64, 64,  98, 1, 4, 1, (short8*)Bf1, 4, 4);
  k_packb<<<NB(18*2*64), 256,0,stream>>>(Wf2, Wf2, 32, 32,  64, 9, 2, 0, (short8*)Bf2, 2, 18);
  k_packb<<<NB(36*6*64), 256,0,stream>>>(Wm,  Wm,  80, 80, 128, 9, 4, 0, (short8*)Bm,  6, 36);
  k_packb<<<NB(72*12*64),256,0,stream>>>(Wz,  Wr,  96, 192,242, 9, 8, 0, (short8*)Bzr, 12, 72);
  k_packb<<<NB(72*6*64), 256,0,stream>>>(Wq,  Wq,  96, 96, 242, 9, 8, 0, (short8*)Bq,  6, 72);
  k_packb<<<NB(27*8*64), 256,0,stream>>>(Wh1, Wh1,128, 128, 96, 9, 3, 0, (short8*)Bh1, 8, 27);
  k_packb<<<NB(36*1*64), 256,0,stream>>>(Wh2, Wh2,  2,   2,128, 9, 4, 0, (short8*)Bh2, 1, 36);
  k_cat2<<<dim3(1), 256, 0, stream>>>(bz, br, bzr, 96);

  // ---- per-scale init ----
  for (int si = 0; si < 3; si++){
    int H = Hs[si], HW = H*H;
    k_init_scale<<<NB(HW*176), 256,0,stream>>>(net_in[si], inp_in[si], netP[si][0],
                                               netS[si][0], hxS[si], coords[si], H, H);
    k_transpose2<<<NB(2*HW*128), 256,0,stream>>>(f2s[si], f1s[si], f2l[si][0], f1h[si], HW);
    for (int l = 1; l < 4; l++){
      int Hl = H >> l;
      k_pool_c4<<<NB(32*Hl*Hl*4), 256,0,stream>>>(f2l[si][l-1], f2l[si][l], Hl, Hl);
    }
  }

  int cur[3] = {0, 0, 0};
  const int seq[6] = {2, 2, 1, 1, 0, 0};
  for (int it = 0; it < 6; it++){
    int si = seq[it];
    int H = Hs[si], W = H, HW = H*W;
    int MT = HW/16;
    float s = (si == 0) ? 2.0f : ((si == 1) ? 4.0f : 8.0f);
    float* netcF = netP[si][cur[si]];
    float* netnF = netP[si][cur[si]^1];
    unsigned short* netcS = netS[si][cur[si]];
    unsigned short* netnS = netS[si][cur[si]^1];
    float* co = coords[si];
    unsigned short* hx = hxS[si];
    unsigned gx = (unsigned)(MT/4);
    bool big = (si == 0);
    bool mid = (si == 1);

    k_corr4<<<dim3((unsigned)HW), 256,0,stream>>>(
        f1h[si], f2l[si][0], f2l[si][1], f2l[si][2], f2l[si][3], co,
        corrS, hx, netcS, H, W);

    // c1 (1x1, corrS -> cminS, relu)
    if (big) k_fgemm<1,7,0,1,0,0,3,1><<<dim3(gx,2), 256,0,stream>>>(corrS,224, nullptr, nullptr,
        (short8*)Bc1, 6, bc1, nullptr,0,0, cminS,128,0, 96, H,W, nullptr,0, nullptr,0);
    else     k_fgemm<1,7,0,1,0,0,2,1><<<dim3(gx,3), 256,0,stream>>>(corrS,224, nullptr, nullptr,
        (short8*)Bc1, 6, bc1, nullptr,0,0, cminS,128,0, 96, H,W, nullptr,0, nullptr,0);
    // f1 (7x7 flow-im2row -> flo1S, relu)
    k_fgemm<1,4,2,1,0,0,2,1><<<dim3(gx,2), 256,0,stream>>>(nullptr,0, nullptr, co,
        (short8*)Bf1, 4, bf1, nullptr,0,0, flo1S,64,0, 64, H,W, nullptr,0, nullptr,0);
    // f2 (3x3, flo1S -> cminS[96..127], relu)
    k_fgemm<3,2,0,1,0,0,2,1><<<dim3(gx,1), 256,0,stream>>>(flo1S,64, nullptr, nullptr,
        (short8*)Bf2, 2, bf2, nullptr,0,0, cminS,128,96, 32, H,W, nullptr,0, nullptr,0);
    // m (3x3, cminS -> hxS[160..239], relu)
    if (big) k_fgemm<3,4,0,1,0,0,3,1><<<dim3(gx,2), 256,0,stream>>>(cminS,128, nullptr, nullptr,
        (short8*)Bm, 6, bm, nullptr,0,0, hx,256,160, 80, H,W, nullptr,0, nullptr,0);
    else     k_fgemm<3,4,0,1,0,0,2,1><<<dim3(gx,3), 256,0,stream>>>(cminS,128, nullptr, nullptr,
        (short8*)Bm, 6, bm, nullptr,0,0, hx,256,160, 80, H,W, nullptr,0, nullptr,0);
    // zr (3x3, hxS -> zrb sigmoid; + rnet hi/lo planes)
    if (big){
      k_fgemm<3,8,0,0,4,0,4,3><<<dim3(gx,3,3), 256,0,stream>>>(hx,256, nullptr, nullptr,
          (short8*)Bzr, 12, bzr, partP,192,0, nullptr,0,0, 192, H,W, nullptr,0, nullptr,0);
      k_red<2,3,3><<<NB(HW*192), 256,0,stream>>>(partP, 192, HW, bzr, zrb, rnetS, nullptr, netcF);
    } else if (mid){
      k_fgemm<3,8,0,0,4,0,2,2><<<dim3(gx,6,2), 256,0,stream>>>(hx,256, nullptr, nullptr,
          (short8*)Bzr, 12, bzr, partP,192,0, nullptr,0,0, 192, H,W, nullptr,0, nullptr,0);
      k_red<2,3,2><<<NB(HW*192), 256,0,stream>>>(partP, 192, HW, bzr, zrb, rnetS, nullptr, netcF);
    } else {
      k_fgemm<3,8,0,2,5,0,2,1><<<dim3(gx,6), 256,0,stream>>>(hx,256, nullptr, nullptr,
          (short8*)Bzr, 12, bzr, zrb,192,0, rnetS,96,0, 192, H,W, nullptr,0, netcF,96);
    }
    // q (3x3, [rnetS | hxS] -> GRU -> netn fp32 + hi/lo)
    if (big){
      k_fgemm<3,8,0,0,4,3,3,3><<<dim3(gx,2,3), 256,0,stream>>>(hx,256, rnetS, nullptr,
          (short8*)Bq, 6, bq, partP,96,0, nullptr,0,0, 96, H,W, nullptr,0, nullptr,0);
      k_red<3,1,3><<<NB(HW*96), 256,0,stream>>>(partP, 96, HW, bq, netnF, netnS, zrb, netcF);
    } else if (mid){
      k_fgemm<3,8,0,0,4,3,2,2><<<dim3(gx,3,2), 256,0,stream>>>(hx,256, rnetS, nullptr,
          (short8*)Bq, 6, bq, partP,96,0, nullptr,0,0, 96, H,W, nullptr,0, nullptr,0);
      k_red<3,1,2><<<NB(HW*96), 256,0,stream>>>(partP, 96, HW, bq, netnF, netnS, zrb, netcF);
    } else {
      k_fgemm<3,8,0,3,1,3,2,1><<<dim3(gx,3), 256,0,stream>>>(hx,256, rnetS, nullptr,
          (short8*)Bq, 6, bq, netnF,96,0, netnS,96,0, 96, H,W, zrb,192, netcF,96);
    }
    // fh1 (3x3, netnS -> t128S, relu)
    if (big){
      k_fgemm<3,3,0,0,4,0,4,3><<<dim3(gx,2,3), 256,0,stream>>>(netnS,96, nullptr, nullptr,
          (short8*)Bh1, 8, bh1, partP,128,0, nullptr,0,0, 128, H,W, nullptr,0, nullptr,0);
      k_red<1,2,3><<<NB(HW*128), 256,0,stream>>>(partP, 128, HW, bh1, nullptr, t128S, nullptr, nullptr);
    } else if (mid){
      k_fgemm<3,3,0,0,4,0,2,2><<<dim3(gx,4,2), 256,0,stream>>>(netnS,96, nullptr, nullptr,
          (short8*)Bh1, 8, bh1, partP,128,0, nullptr,0,0, 128, H,W, nullptr,0, nullptr,0);
      k_red<1,2,2><<<NB(HW*128), 256,0,stream>>>(partP, 128, HW, bh1, nullptr, t128S, nullptr, nullptr);
    } else {
      k_fgemm<3,3,0,1,0,0,2,1><<<dim3(gx,4), 256,0,stream>>>(netnS,96, nullptr, nullptr,
          (short8*)Bh1, 8, bh1, nullptr,0,0, t128S,128,0, 128, H,W, nullptr,0, nullptr,0);
    }
    // fh2 (3x3, t128S -> coords CHW +=)
    k_fgemm<3,4,0,0,2,0,1,1><<<dim3(gx,1), 256,0,stream>>>(t128S,128, nullptr, nullptr,
        (short8*)Bh2, 1, bh2, co,0,0, nullptr,0,0, 2, H,W, nullptr,0, nullptr,0);

    int Hf = (si > 0) ? Hs[si-1] : 0;
    float* conext = (si > 0) ? coords[si-1] : nullptr;
    k_upflow2<<<NB(2*192*192 + (Hf ? 2*Hf*Hf : 0)), 256,0,stream>>>(
        co, (float*)d_out + (size_t)it*2*192*192, H, W, s, conext, Hf);

    cur[si] ^= 1;
  }
  #undef NB
}